// Round 8
// baseline (491.175 us; speedup 1.0000x reference)
//
#include <hip/hip_runtime.h>
#include <hip/hip_bf16.h>

// Problem constants (match reference)
constexpr int B = 8192;
constexpr int G = 1024;
constexpr int E = 256;
constexpr int K = 2048;
constexpr float P_NULL = 0.1f;
constexpr int N_STEP = 4;

typedef unsigned short u16;
typedef short bf16x8 __attribute__((ext_vector_type(8)));
typedef float f32x4 __attribute__((ext_vector_type(4)));

// raw-sync primitives (step kernel pipelining)
#define S_BARRIER __builtin_amdgcn_s_barrier()
#define SCHED0 __builtin_amdgcn_sched_barrier(0)
#define WAIT_VM0 asm volatile("s_waitcnt vmcnt(0)" ::: "memory")
#define WAIT_LGKM0 asm volatile("s_waitcnt lgkmcnt(0)" ::: "memory")

// ---------------------------------------------------------------------------
// bf16 <-> f32 (RNE)
// ---------------------------------------------------------------------------
__device__ inline u16 f2bf(float f) {
    union { float f; uint32_t u; } cv;
    cv.f = f;
    const uint32_t u = cv.u;
    return (u16)((u + 0x7fffu + ((u >> 16) & 1u)) >> 16);
}
__device__ inline float bf2f(u16 h) {
    union { uint32_t u; float f; } cv;
    cv.u = ((uint32_t)h) << 16;
    return cv.f;
}
__device__ inline uint4 pack8(const float* v) {
    uint4 u;
    u.x = (uint32_t)f2bf(v[0]) | ((uint32_t)f2bf(v[1]) << 16);
    u.y = (uint32_t)f2bf(v[2]) | ((uint32_t)f2bf(v[3]) << 16);
    u.z = (uint32_t)f2bf(v[4]) | ((uint32_t)f2bf(v[5]) << 16);
    u.w = (uint32_t)f2bf(v[6]) | ((uint32_t)f2bf(v[7]) << 16);
    return u;
}

// async global->LDS, 16B per lane (LDS dest is lane-linear; global src is
// per-lane and may be permuted -> XOR-swizzle is applied on the GLOBAL side)
typedef __attribute__((address_space(1))) const void* gaddr_t;
typedef __attribute__((address_space(3))) void* laddr_t;
__device__ inline void gload_lds16(const void* g, void* l) {
    __builtin_amdgcn_global_load_lds((gaddr_t)g, (laddr_t)l, 16, 0, 0);
}

// XCD-aware tile swizzle (requires gridDim.y % 8 == 0)
__device__ inline void swizzle_tiles(int& tr, int& tc) {
    const int cx = gridDim.x, cy = gridDim.y;
    const int id = blockIdx.y * cx + blockIdx.x;
    const int k = id & 7;
    const int q = id >> 3;
    tr = k * (cy >> 3) + q / cx;
    tc = q % cx;
}

// ---------------------------------------------------------------------------
// Reduction helpers (256-thread blocks, wave64)
// ---------------------------------------------------------------------------
__device__ inline float wave_sum(float v) {
#pragma unroll
    for (int off = 32; off > 0; off >>= 1) v += __shfl_down(v, off, 64);
    return v;
}
__device__ inline float block_sum256(float v, float* sm) {
    v = wave_sum(v);
    const int w = threadIdx.x >> 6;
    if ((threadIdx.x & 63) == 0) sm[w] = v;
    __syncthreads();
    const float r = sm[0] + sm[1] + sm[2] + sm[3];
    __syncthreads();
    return r;
}

// ---------------------------------------------------------------------------
// f32 -> bf16 flat convert, 8 elems/thread
// ---------------------------------------------------------------------------
__global__ __launch_bounds__(256) void f2bf_kernel(
    const float* __restrict__ in, u16* __restrict__ out, int n) {
    const int i = (blockIdx.x * 256 + threadIdx.x) * 8;
    if (i + 7 >= n) {
        for (int j = i; j < n; ++j) out[j] = f2bf(in[j]);
        return;
    }
    const float4 a = *(const float4*)(in + i);
    const float4 b = *(const float4*)(in + i + 4);
    float v[8] = {a.x, a.y, a.z, a.w, b.x, b.y, b.z, b.w};
    *(uint4*)(out + i) = pack8(v);
}

// ---------------------------------------------------------------------------
// Fused prep: f32 (R,C) -> bf16 (R,C) copy + bf16 (C,R) transpose +
// csq[c] += (1/R) sum_r v^2.  grid (C/32, R/32), block 256.
// ---------------------------------------------------------------------------
__global__ __launch_bounds__(256) void prep_kernel(
    const float* __restrict__ in, u16* __restrict__ outN,
    u16* __restrict__ outT, float* __restrict__ csq, int R, int C,
    float inv_R) {
    __shared__ float tile[32][33];
    __shared__ float sred[8][32];
    const int bx = blockIdx.x * 32, by = blockIdx.y * 32;
    const int x = threadIdx.x & 31, y0 = threadIdx.x >> 5;
    float s = 0.f;
#pragma unroll
    for (int yy = 0; yy < 32; yy += 8) {
        const float v = in[(size_t)(by + y0 + yy) * C + bx + x];
        tile[y0 + yy][x] = v;
        outN[(size_t)(by + y0 + yy) * C + bx + x] = f2bf(v);
        s = fmaf(v, v, s);
    }
    sred[y0][x] = s;
    __syncthreads();
#pragma unroll
    for (int yy = 0; yy < 32; yy += 8)
        outT[(size_t)(bx + y0 + yy) * R + by + x] = f2bf(tile[x][y0 + yy]);
    if (y0 == 0) {
        float t = 0.f;
#pragma unroll
        for (int k2 = 0; k2 < 8; ++k2) t += sred[k2][x];
        atomicAdd(csq + bx + x, t * inv_R);
    }
}

// ---------------------------------------------------------------------------
// MFMA bf16 GEMM, 256x256 tile, 512 threads / 8 waves (R8, encode/decode):
// u = exp(alpha*acc - bias[col]) -> bf16 C; Saux[row] += row-sum.
// R6/R7 post-mortem: a 1024-thread block is inherently 4 waves/EU -> hard
// 128-reg/wave cap; acc[4][4]x16waves spilled (VGPR_Count=64, WRITE_SIZE
// +35MB scratch). Correct 256^2 geometry is HipKittens': 8 waves, 128x64
// out/wave = acc[8][4] (128 AGPR) + af[8]/bfr[4] (~48 VGPR) ~= 200 unified
// regs, fits (512,2)'s 256 cap (R5-verified). Per-CU ingest: A x8 + B x32
// = 256MB -> 1MB/CU (vs R5 256x128's 1.5MB -> 51us).
// Wave (wrh = w>>2: row-half, wcq = w&3: col-quarter).
// Epilogue: two row-half phases, 4 patches x 128x64 u16 = 64KB LDS each.
// ---------------------------------------------------------------------------
__global__ __launch_bounds__(512, 2) void mfma_big_kernel(
    const u16* __restrict__ A, const u16* __restrict__ Bm,
    u16* __restrict__ C, const float* __restrict__ bias,
    float* __restrict__ Saux, int M, int N, int Kd, float alpha) {
    __shared__ u16 smem[32768];  // loop: As 16384 u16 | Bs 16384 u16
    u16* As = smem;
    u16* Bs = smem + 16384;
    const int tid = threadIdx.x;
    int btr, btc;
    swizzle_tiles(btr, btc);
    const int row0 = btr * 256, col0 = btc * 256;
    const int lane = tid & 63, wave = tid >> 6;
    const int wrh = wave >> 2, wcq = wave & 3;  // row-half, col-quarter
    const int tx = lane & 15, quad = lane >> 4;
    const int txl = tx & 7;

    f32x4 acc[8][4] = {};

    for (int k0 = 0; k0 < Kd; k0 += 64) {
#pragma unroll
        for (int l = 0; l < 4; ++l) {
            const int lin = l * 4096 + tid * 8;
            const int r = lin >> 6;
            const int c = (((lin >> 3) & 7) ^ (r & 7)) * 8;  // XOR-swizzled src
            gload_lds16(A + (size_t)(row0 + r) * Kd + k0 + c, &As[lin]);
        }
#pragma unroll
        for (int l = 0; l < 4; ++l) {
            const int lin = l * 4096 + tid * 8;
            const int r = lin >> 6;
            const int c = (((lin >> 3) & 7) ^ (r & 7)) * 8;
            gload_lds16(Bm + (size_t)(col0 + r) * Kd + k0 + c, &Bs[lin]);
        }
        __syncthreads();
#pragma unroll
        for (int ks = 0; ks < 2; ++ks) {
            bf16x8 af[8], bfr[4];
            const int gsw = ((ks * 4 + quad) ^ txl) * 8;
#pragma unroll
            for (int i = 0; i < 8; ++i)
                af[i] = *(const bf16x8*)&As[(wrh * 128 + i * 16 + tx) * 64 + gsw];
#pragma unroll
            for (int j = 0; j < 4; ++j)
                bfr[j] = *(const bf16x8*)&Bs[(wcq * 64 + j * 16 + tx) * 64 + gsw];
#pragma unroll
            for (int i = 0; i < 8; ++i)
#pragma unroll
                for (int j = 0; j < 4; ++j)
                    acc[i][j] = __builtin_amdgcn_mfma_f32_16x16x32_bf16(
                        af[i], bfr[j], acc[i][j], 0, 0, 0);
        }
        __syncthreads();
    }

    // ---- epilogue, two row-half phases; 4 patches x 128x64 u16 = 64KB ----
    const int pbase = wcq * 8192;  // this wave's patch (128 rows x 64 cols)
    for (int ph = 0; ph < 2; ++ph) {
        if (wrh == ph) {
#pragma unroll
            for (int i = 0; i < 8; ++i) {
                float sr[4] = {0.f, 0.f, 0.f, 0.f};
#pragma unroll
                for (int j = 0; j < 4; ++j) {
                    const int pcol = j * 16 + tx;
                    const float cb = bias[col0 + wcq * 64 + pcol];
#pragma unroll
                    for (int r = 0; r < 4; ++r) {
                        const int prow = i * 16 + quad * 4 + r;  // 0..127
                        const int paddr = pbase + prow * 64 +
                            (((pcol >> 3) ^ (prow & 7)) << 3) + (pcol & 7);
                        const float v = __expf(fmaf(acc[i][j][r], alpha, -cb));
                        sr[r] += v;
                        smem[paddr] = f2bf(v);
                    }
                }
#pragma unroll
                for (int r = 0; r < 4; ++r) {
                    float s = sr[r];
                    s += __shfl_xor(s, 1, 64);
                    s += __shfl_xor(s, 2, 64);
                    s += __shfl_xor(s, 4, 64);
                    s += __shfl_xor(s, 8, 64);
                    if (tx == 0)
                        atomicAdd(
                            &Saux[row0 + wrh * 128 + i * 16 + quad * 4 + r], s);
                }
            }
        }
        __syncthreads();
        // store rows ph*128 .. ph*128+127 (4 threads/row, 64B segments)
        const int rr = tid >> 2;       // 0..127
        const int cg = tid & 3;
#pragma unroll
        for (int u = 0; u < 8; ++u) {
            const int c = u * 32 + cg * 8;       // 0..255, 16B aligned
            const int patch = c >> 6;
            const int cl = c & 63;
            const int pg = ((cl >> 3) ^ (rr & 7)) << 3;
            *(uint4*)(C + (size_t)(row0 + ph * 128 + rr) * N + col0 + c) =
                *(const uint4*)&smem[patch * 8192 + rr * 64 + pg];
        }
        __syncthreads();
    }
}

// ---------------------------------------------------------------------------
// MFMA bf16 GEMM, 128x64 tile, z0 = (e @ xb^T) / S_enc[row].
// 256 blocks (1/CU): per-CU staged 0.75MB.
// ---------------------------------------------------------------------------
__global__ __launch_bounds__(256) void mfma_zdiv_kernel(
    const u16* __restrict__ A, const u16* __restrict__ Bm,
    u16* __restrict__ C, const float* __restrict__ Srow,
    int M, int N, int Kd) {
    __shared__ u16 As[128 * 64];
    __shared__ u16 Bs[64 * 64];
    const int tid = threadIdx.x;
    int btr, btc;
    swizzle_tiles(btr, btc);
    const int row0 = btr * 128, col0 = btc * 64;
    const int lane = tid & 63, wave = tid >> 6;  // wave = 32-row band (0..3)
    const int tx = lane & 15, quad = lane >> 4;
    const int txl = tx & 7;

    f32x4 acc[2][4] = {};

    for (int k0 = 0; k0 < Kd; k0 += 64) {
#pragma unroll
        for (int l = 0; l < 4; ++l) {
            const int lin = l * 2048 + tid * 8;
            const int r = lin >> 6;
            const int c = (((lin >> 3) & 7) ^ (r & 7)) * 8;
            gload_lds16(A + (size_t)(row0 + r) * Kd + k0 + c, &As[lin]);
        }
#pragma unroll
        for (int l = 0; l < 2; ++l) {
            const int lin = l * 2048 + tid * 8;
            const int r = lin >> 6;
            const int c = (((lin >> 3) & 7) ^ (r & 7)) * 8;
            gload_lds16(Bm + (size_t)(col0 + r) * Kd + k0 + c, &Bs[lin]);
        }
        __syncthreads();
#pragma unroll
        for (int ks = 0; ks < 2; ++ks) {
            bf16x8 af[2], bfr[4];
            const int gsw = ((ks * 4 + quad) ^ txl) * 8;
#pragma unroll
            for (int i = 0; i < 2; ++i)
                af[i] = *(const bf16x8*)&As[(wave * 32 + i * 16 + tx) * 64 + gsw];
#pragma unroll
            for (int j = 0; j < 4; ++j)
                bfr[j] = *(const bf16x8*)&Bs[(j * 16 + tx) * 64 + gsw];
#pragma unroll
            for (int i = 0; i < 2; ++i)
#pragma unroll
                for (int j = 0; j < 4; ++j)
                    acc[i][j] = __builtin_amdgcn_mfma_f32_16x16x32_bf16(
                        af[i], bfr[j], acc[i][j], 0, 0, 0);
        }
        __syncthreads();
    }

#pragma unroll
    for (int i = 0; i < 2; ++i)
#pragma unroll
        for (int r = 0; r < 4; ++r) {
            const int row = row0 + wave * 32 + i * 16 + quad * 4 + r;
            const float sc = 1.0f / Srow[row];
#pragma unroll
            for (int j = 0; j < 4; ++j) {
                const int col = col0 + j * 16 + tx;
                C[(size_t)row * N + col] = f2bf(acc[i][j][r] * sc);
            }
        }
}

// ---------------------------------------------------------------------------
// STEP (R4 structure, kept): K-split partial kernel. 128 rows/block x P=4
// K-parts -> grid 256 (1/CU). Blocks write f32 z' partials Zp[4][B][E] +
// Sw partials Sp[4][B]; norm_kernel sums parts, divides, writes z bf16.
// ---------------------------------------------------------------------------
constexpr int XBTS0 = 0;          // [32k][256e] granule-XOR8
constexpr int XBTS1 = 8192;
constexpr int XBS0 = 16384;       // [256e][32k] granule-XOR4 (involution)
constexpr int XBS1 = 24576;
constexpr int ES0 = 32768;        // [128r][40k-padded]
constexpr int ES1 = 37888;
constexpr int WSO = 43008;        // [128r][40k-padded]
constexpr int SMEM_U16 = 48128;

__global__ __launch_bounds__(512, 2) void step_part_kernel(
    const u16* __restrict__ Z,      // (B,E) current z
    const u16* __restrict__ XbT,    // (K,E)
    const u16* __restrict__ Xb,     // (E,K)
    const u16* __restrict__ Ebf,    // (B,K) unnormalized encode weights
    const float* __restrict__ c2b,  // (K)
    float* __restrict__ Zp,         // (4,B,E) f32 partials
    float* __restrict__ Sp) {       // (4,B) f32 partials
    __shared__ u16 smem[SMEM_U16];
    __shared__ float redS[2][128];
    const int tid = threadIdx.x;
    const int lane = tid & 63, wave = tid >> 6;
    const int wh = wave >> 1, wk = wave & 1;  // 32-row band, k/e-half
    const int tx = lane & 15, quad = lane >> 4;
    const int part = blockIdx.x & 3;
    const int row0 = (blockIdx.x >> 2) * 128;
    const int kbase = part * 512;
    const float ascale = 2.0f / (float)E;
    const int kcol = wk * 16 + tx;            // lane's k-col in chunk (0..31)
    const int erow_ = tid >> 2;               // e stage: row (0..127)
    const int eg_ = tid & 3;                  // e stage: 8-col group
    const int ewaddr = erow_ * 40 + eg_ * 8;  // padded es/ws row stride 40 u16

    // ---- prologue: z band -> region A ([128r][256e], granule-XOR8) ----
#pragma unroll
    for (int l = 0; l < 8; ++l) {
        const int lin = l * 4096 + tid * 8;
        const int r = lin >> 8, gf = (lin >> 3) & 31;
        const int eoff = ((gf & 24) | ((gf & 7) ^ (r & 7))) << 3;
        gload_lds16(Z + (size_t)(row0 + r) * E + eoff, &smem[lin]);
    }
    // e chunk 0 -> regs ; cb
    uint4 ereg = *(const uint4*)&Ebf[(size_t)(row0 + erow_) * K + kbase + eg_ * 8];
    float cb = c2b[kbase + kcol];
    WAIT_VM0;
    SCHED0;
    S_BARRIER;
    SCHED0;

    // z A-frags: af[i][s] = z[wh*32+i*16+tx][e = s*32+quad*8 ..]
    bf16x8 af[2][8];
#pragma unroll
    for (int i = 0; i < 2; ++i) {
        const int row = wh * 32 + i * 16 + tx;
#pragma unroll
        for (int s = 0; s < 8; ++s) {
            const int g = s * 4 + quad;
            const int gp = (g & 24) | ((g & 7) ^ (row & 7));
            af[i][s] = *(const bf16x8*)&smem[row * 256 + gp * 8];
        }
    }
    // es[0] write (region separate from A)
    *(uint4*)&smem[ES0 + ewaddr] = ereg;
    WAIT_LGKM0;  // af reads + es0 write done before region A is overwritten
    SCHED0;
    S_BARRIER;
    SCHED0;

    // stage chunk 0 into buffers 0
#pragma unroll
    for (int l = 0; l < 2; ++l) {
        const int lin = l * 4096 + tid * 8;
        const int r = lin >> 8, gf = (lin >> 3) & 31;
        const int eoff = ((gf & 24) | ((gf & 7) ^ (r & 7))) << 3;
        gload_lds16(XbT + (size_t)(kbase + r) * E + eoff, &smem[XBTS0 + lin]);
    }
#pragma unroll
    for (int l = 0; l < 2; ++l) {
        const int lin = l * 4096 + tid * 8;
        const int e = lin >> 5, gq = (lin >> 3) & 3;
        const int koff = (gq ^ (e & 3) ^ ((e >> 2) & 3)) << 3;
        gload_lds16(Xb + (size_t)e * K + kbase + koff, &smem[XBS0 + lin]);
    }
    WAIT_VM0;
    SCHED0;
    S_BARRIER;
    SCHED0;

    f32x4 acc2[2][8] = {};  // z' partial acc: [row-half i][e-frag f]
    float srow[2][4] = {};  // Sw partials

    for (int kc = 0; kc < 16; ++kc) {
        const int p = kc & 1;
        const int xbtsP = p ? XBTS1 : XBTS0;
        const int xbsP = p ? XBS1 : XBS0;
        float cbn = 0.f;
        // ---- 1. stage chunk kc+1 (4 gload_lds) + e kc+1 (reg) ----
        if (kc < 15) {
            const int kn0 = kbase + (kc + 1) * 32;
            const int xbtsN = p ? XBTS0 : XBTS1;
            const int xbsN = p ? XBS0 : XBS1;
#pragma unroll
            for (int l = 0; l < 2; ++l) {
                const int lin = l * 4096 + tid * 8;
                const int r = lin >> 8, gf = (lin >> 3) & 31;
                const int eoff = ((gf & 24) | ((gf & 7) ^ (r & 7))) << 3;
                gload_lds16(XbT + (size_t)(kn0 + r) * E + eoff,
                            &smem[xbtsN + lin]);
            }
#pragma unroll
            for (int l = 0; l < 2; ++l) {
                const int lin = l * 4096 + tid * 8;
                const int e = lin >> 5, gq = (lin >> 3) & 3;
                const int koff = (gq ^ (e & 3) ^ ((e >> 2) & 3)) << 3;
                gload_lds16(Xb + (size_t)e * K + kn0 + koff,
                            &smem[xbsN + lin]);
            }
            ereg = *(const uint4*)&Ebf[(size_t)(row0 + erow_) * K + kn0 + eg_ * 8];
            cbn = c2b[kn0 + kcol];
        }
        SCHED0;  // pin stage issue above compute

        // ---- 2. t-part: ta[i] = z(band rows) @ xbT(k-col = kcol) ----
        bf16x8 bfr[8];
#pragma unroll
        for (int s = 0; s < 8; ++s) {
            const int g = s * 4 + quad;
            const int gp = (g & 24) | ((g & 7) ^ (kcol & 7));
            bfr[s] = *(const bf16x8*)&smem[xbtsP + kcol * 256 + gp * 8];
        }
        f32x4 ta[2] = {};
#pragma unroll
        for (int s = 0; s < 8; ++s)
#pragma unroll
            for (int i = 0; i < 2; ++i)
                ta[i] = __builtin_amdgcn_mfma_f32_16x16x32_bf16(
                    af[i][s], bfr[s], ta[i], 0, 0, 0);

        // ---- 3. epilogue: w = e * exp(t*ascale - cb) -> ws; Sw partial ----
        const int esP = p ? ES1 : ES0;
#pragma unroll
        for (int i = 0; i < 2; ++i)
#pragma unroll
            for (int r = 0; r < 4; ++r) {
                const int prow = wh * 32 + i * 16 + quad * 4 + r;
                const int paddr = prow * 40 + kcol;
                const float ev = bf2f(smem[esP + paddr]);
                const float wv = ev * __expf(fmaf(ta[i][r], ascale, -cb));
                srow[i][r] += wv;
                smem[WSO + paddr] = f2bf(wv);
            }
        // ---- B1: ws visible cross-wave (k-halves); vm loads in flight ----
        WAIT_LGKM0;
        SCHED0;
        S_BARRIER;
        SCHED0;

        // ---- 4. z-part: acc2 += w(band, 32k) @ xbT(32k, e=wk*128..) ----
        bf16x8 a2[2];
#pragma unroll
        for (int i = 0; i < 2; ++i) {
            const int row = wh * 32 + i * 16 + tx;
            a2[i] = *(const bf16x8*)&smem[WSO + row * 40 + quad * 8];
        }
#pragma unroll
        for (int f = 0; f < 8; ++f) {
            const int ecol = wk * 128 + f * 16 + tx;
            const int gq = quad ^ (ecol & 3) ^ ((ecol >> 2) & 3);
            const bf16x8 b2 = *(const bf16x8*)&smem[xbsP + ecol * 32 + gq * 8];
#pragma unroll
            for (int i = 0; i < 2; ++i)
                acc2[i][f] = __builtin_amdgcn_mfma_f32_16x16x32_bf16(
                    a2[i], b2, acc2[i][f], 0, 0, 0);
        }
        // ---- 5. es(kc+1) write (compiler waits vmcnt for ereg) ----
        if (kc < 15) {
            const int esN = p ? ES0 : ES1;
            *(uint4*)&smem[esN + ewaddr] = ereg;
        }
        cb = cbn;
        // ---- B2: chunk kc+1 staged + es write visible; dbuf swap safe ----
        WAIT_LGKM0;
        SCHED0;
        WAIT_VM0;
        S_BARRIER;
        SCHED0;
    }

    // ---- Sw partials: reduce over tx, combine wk-halves via LDS ----
#pragma unroll
    for (int i = 0; i < 2; ++i)
#pragma unroll
        for (int r = 0; r < 4; ++r) {
            float s = srow[i][r];
            s += __shfl_xor(s, 1, 64);
            s += __shfl_xor(s, 2, 64);
            s += __shfl_xor(s, 4, 64);
            s += __shfl_xor(s, 8, 64);
            if (tx == 0) redS[wk][wh * 32 + i * 16 + quad * 4 + r] = s;
        }
    __syncthreads();
    if (tid < 128)
        Sp[(size_t)part * B + row0 + tid] = redS[0][tid] + redS[1][tid];

    // ---- Zp stores: f32 partials, coalesced in tx ----
#pragma unroll
    for (int i = 0; i < 2; ++i)
#pragma unroll
        for (int f = 0; f < 8; ++f)
#pragma unroll
            for (int r = 0; r < 4; ++r) {
                const int row = wh * 32 + i * 16 + quad * 4 + r;
                const int e = wk * 128 + f * 16 + tx;
                Zp[((size_t)part * B + row0 + row) * E + e] = acc2[i][f][r];
            }
}

// ---------------------------------------------------------------------------
// norm: z[row][e] = (sum_p Zp[p][row][e]) / (sum_p Sp[p][row]) -> bf16
// grid B*E/2048 = 1024, block 256, 8 elems/thread.
// ---------------------------------------------------------------------------
__global__ __launch_bounds__(256) void norm_kernel(
    const float* __restrict__ Zp, const float* __restrict__ Sp,
    u16* __restrict__ Z) {
    const int gidx = blockIdx.x * 256 + threadIdx.x;
    const int row = gidx >> 5;
    const int e0 = (gidx & 31) * 8;
    const float s = Sp[row] + Sp[B + row] + Sp[2 * B + row] + Sp[3 * B + row];
    const float inv = 1.0f / s;
    const size_t base = (size_t)row * E + e0;
    float4 a0 = *(const float4*)(Zp + base);
    float4 a1 = *(const float4*)(Zp + base + 4);
#pragma unroll
    for (int p = 1; p < 4; ++p) {
        const float4 b0 = *(const float4*)(Zp + (size_t)p * B * E + base);
        const float4 b1 = *(const float4*)(Zp + (size_t)p * B * E + base + 4);
        a0.x += b0.x; a0.y += b0.y; a0.z += b0.z; a0.w += b0.w;
        a1.x += b1.x; a1.y += b1.y; a1.z += b1.z; a1.w += b1.w;
    }
    float v[8] = {a0.x * inv, a0.y * inv, a0.z * inv, a0.w * inv,
                  a1.x * inv, a1.y * inv, a1.z * inv, a1.w * inv};
    *(uint4*)(Z + base) = pack8(v);
}

// ---------------------------------------------------------------------------
// MFMA bf16 GEMM (128x128 tile) with fused MSE-loss epilogue:
// D = P_NULL*exp(x2[row]) + S0[row];
// loss[row] += (1/N)*sum_col (acc/D - X[row,col])^2
// ---------------------------------------------------------------------------
__global__ __launch_bounds__(256) void mfma_loss_kernel(
    const u16* __restrict__ A, const u16* __restrict__ Bm,
    float* __restrict__ loss, const float* __restrict__ x2,
    const float* __restrict__ X, const float* __restrict__ S0,
    int M, int N, int Kd) {
    __shared__ u16 As[128 * 64];
    __shared__ u16 Bs[128 * 64];
    const int tid = threadIdx.x;
    int btr, btc;
    swizzle_tiles(btr, btc);
    const int row0 = btr * 128, col0 = btc * 128;
    const int lane = tid & 63, wave = tid >> 6;
    const int wr = (wave >> 1) * 64, wc = (wave & 1) * 64;
    const int tx = lane & 15, quad = lane >> 4;
    const int txl = tx & 7;

    f32x4 acc[4][4] = {};

    for (int k0 = 0; k0 < Kd; k0 += 64) {
#pragma unroll
        for (int l = 0; l < 4; ++l) {
            const int lin = l * 2048 + tid * 8;
            const int r = lin >> 6;
            const int c = (((lin >> 3) & 7) ^ (r & 7)) * 8;
            gload_lds16(A + (size_t)(row0 + r) * Kd + k0 + c, &As[lin]);
        }
#pragma unroll
        for (int l = 0; l < 4; ++l) {
            const int lin = l * 2048 + tid * 8;
            const int r = lin >> 6;
            const int c = (((lin >> 3) & 7) ^ (r & 7)) * 8;
            gload_lds16(Bm + (size_t)(col0 + r) * Kd + k0 + c, &Bs[lin]);
        }
        __syncthreads();
#pragma unroll
        for (int ks = 0; ks < 2; ++ks) {
            bf16x8 af[4], bfr[4];
            const int gsw = ((ks * 4 + quad) ^ txl) * 8;
#pragma unroll
            for (int i = 0; i < 4; ++i)
                af[i] = *(const bf16x8*)&As[(wr + i * 16 + tx) * 64 + gsw];
#pragma unroll
            for (int j = 0; j < 4; ++j)
                bfr[j] = *(const bf16x8*)&Bs[(wc + j * 16 + tx) * 64 + gsw];
#pragma unroll
            for (int i = 0; i < 4; ++i)
#pragma unroll
                for (int j = 0; j < 4; ++j)
                    acc[i][j] = __builtin_amdgcn_mfma_f32_16x16x32_bf16(
                        af[i], bfr[j], acc[i][j], 0, 0, 0);
        }
        __syncthreads();
    }

    const float inv_n = 1.0f / (float)N;
#pragma unroll
    for (int i = 0; i < 4; ++i) {
#pragma unroll
        for (int r = 0; r < 4; ++r) {
            const int row = row0 + wr + i * 16 + quad * 4 + r;
            const float D = P_NULL * __expf(x2[row]) + S0[row];
            const float invD = 1.0f / D;
            float s = 0.f;
#pragma unroll
            for (int j = 0; j < 4; ++j) {
                const int col = col0 + wc + j * 16 + tx;
                const float d = acc[i][j][r] * invD - X[(size_t)row * N + col];
                s = fmaf(d, d, s);
            }
            s += __shfl_xor(s, 1, 64);
            s += __shfl_xor(s, 2, 64);
            s += __shfl_xor(s, 4, 64);
            s += __shfl_xor(s, 8, 64);
            if (tx == 0) atomicAdd(&loss[row], s * inv_n);
        }
    }
}

// ---------------------------------------------------------------------------
// Row mean of squares of Z (B,E) bf16: x2[row] = mean(Z[row,:]^2)
// ---------------------------------------------------------------------------
__global__ __launch_bounds__(256) void rowmeansq_bf_kernel(
    const u16* __restrict__ Z, float* __restrict__ out) {
    __shared__ float sm[4];
    const float v = bf2f(Z[(size_t)blockIdx.x * E + threadIdx.x]);
    const float s = block_sum256(v * v, sm);
    if (threadIdx.x == 0) out[blockIdx.x] = s * (1.0f / (float)E);
}

// ---------------------------------------------------------------------------
extern "C" void kernel_launch(void* const* d_in, const int* in_sizes, int n_in,
                              void* d_out, int out_size, void* d_ws, size_t ws_size,
                              hipStream_t stream) {
    const float* images = (const float*)d_in[0];  // (B,G)
    const float* xa     = (const float*)d_in[1];  // (G,K)
    const float* xb     = (const float*)d_in[2];  // (E,K)
    float* out = (float*)d_out;                   // (B,)

    // workspace carve-up (u16 elements, all regions 16B-aligned)
    u16* img_bf = (u16*)d_ws;                      // B*G
    u16* xa_bf  = img_bf + (size_t)B * G;          // G*K
    u16* xaT_bf = xa_bf + (size_t)G * K;           // K*G
    u16* xb_bf  = xaT_bf + (size_t)K * G;          // E*K
    u16* xbT_bf = xb_bf + (size_t)E * K;           // K*E
    u16* e_bf   = xbT_bf + (size_t)K * E;          // B*K (unnormalized enc e)
    u16* wu_bf  = e_bf + (size_t)B * K;            // B*K (decode u)
    u16* z_bf   = wu_bf + (size_t)B * K;           // B*E
    float* c2a  = (float*)(z_bf + (size_t)B * E);  // K   --+ one memset
    float* c2b  = c2a + K;                         // K     |
    float* Svec = c2b + K;                         // 2*B --+ (S_enc, S0)
    float* x2z  = Svec + 2 * B;                    // B (fully written)
    float* Sp   = x2z + B;                         // 4*B (fully written/step)
    // Zp (4,B,E) f32 = 32MB overlays wu_bf (B*K u16 = 32MB; wu only used
    // in decode, after the step loop).
    float* Zp = (float*)wu_bf;

    (void)hipMemsetAsync(d_out, 0, (size_t)B * sizeof(float), stream);
    (void)hipMemsetAsync(c2a, 0, (size_t)(2 * K + 2 * B) * sizeof(float), stream);

    // prep: bf16 copies + transposes + column mean-squares (one read each)
    f2bf_kernel<<<(B * G) / 2048, 256, 0, stream>>>(images, img_bf, B * G);
    prep_kernel<<<dim3(K / 32, G / 32), 256, 0, stream>>>(
        xa, xa_bf, xaT_bf, c2a, G, K, 1.0f / (float)G);
    prep_kernel<<<dim3(K / 32, E / 32), 256, 0, stream>>>(
        xb, xb_bf, xbT_bf, c2b, E, K, 1.0f / (float)E);

    // encode (softmax eliminated): e = exp(images@xa*(2/G) - c2a), S_enc=rowsum
    float* S_enc = Svec;
    mfma_big_kernel<<<dim3(K / 256, B / 256), 512, 0, stream>>>(
        img_bf, xaT_bf, e_bf, c2a, S_enc, B, K, G, 2.0f / (float)G);

    // z0 = (e @ xb^T) / S_enc[row]   (== pik @ xb^T)
    mfma_zdiv_kernel<<<dim3(E / 64, B / 128), 256, 0, stream>>>(
        e_bf, xb_bf, z_bf, S_enc, B, E, K);

    // loop: K-split partial steps + normalize (w never hits HBM)
    for (int s = 0; s < N_STEP; ++s) {
        step_part_kernel<<<256, 512, 0, stream>>>(
            z_bf, xbT_bf, xb_bf, e_bf, c2b, Zp, Sp);
        norm_kernel<<<(B * E) / 2048, 256, 0, stream>>>(Zp, Sp, z_bf);
    }

    // decode: x2 = mean(z^2) ; u = exp(z@xb*(2/E) - c2b) ; S0 = rowsum(u)
    float* S0 = Svec + B;
    rowmeansq_bf_kernel<<<B, 256, 0, stream>>>(z_bf, x2z);
    mfma_big_kernel<<<dim3(K / 256, B / 256), 512, 0, stream>>>(
        z_bf, xbT_bf, wu_bf, c2b, S0, B, K, E, 2.0f / (float)E);

    // loss: recon = (u @ xa^T)/D[row], D = P_NULL*e^{x2}+S0 ;
    // loss[b] = mean_g (recon - images)^2
    mfma_loss_kernel<<<dim3(G / 128, B / 128), 256, 0, stream>>>(
        wu_bf, xa_bf, out, x2z, images, S0, B, G, K);
}

// Round 10
// 464.827 us; speedup vs baseline: 1.0567x; 1.0567x over previous
//
#include <hip/hip_runtime.h>
#include <hip/hip_bf16.h>

// Problem constants (match reference)
constexpr int B = 8192;
constexpr int G = 1024;
constexpr int E = 256;
constexpr int K = 2048;
constexpr float P_NULL = 0.1f;
constexpr int N_STEP = 4;

typedef unsigned short u16;
typedef short bf16x8 __attribute__((ext_vector_type(8)));
typedef float f32x4 __attribute__((ext_vector_type(4)));

// raw-sync primitives (step kernel pipelining)
#define S_BARRIER __builtin_amdgcn_s_barrier()
#define SCHED0 __builtin_amdgcn_sched_barrier(0)
#define WAIT_VM0 asm volatile("s_waitcnt vmcnt(0)" ::: "memory")
#define WAIT_LGKM0 asm volatile("s_waitcnt lgkmcnt(0)" ::: "memory")

// ---------------------------------------------------------------------------
// bf16 <-> f32 (RNE)
// ---------------------------------------------------------------------------
__device__ inline u16 f2bf(float f) {
    union { float f; uint32_t u; } cv;
    cv.f = f;
    const uint32_t u = cv.u;
    return (u16)((u + 0x7fffu + ((u >> 16) & 1u)) >> 16);
}
__device__ inline float bf2f(u16 h) {
    union { uint32_t u; float f; } cv;
    cv.u = ((uint32_t)h) << 16;
    return cv.f;
}
__device__ inline uint4 pack8(const float* v) {
    uint4 u;
    u.x = (uint32_t)f2bf(v[0]) | ((uint32_t)f2bf(v[1]) << 16);
    u.y = (uint32_t)f2bf(v[2]) | ((uint32_t)f2bf(v[3]) << 16);
    u.z = (uint32_t)f2bf(v[4]) | ((uint32_t)f2bf(v[5]) << 16);
    u.w = (uint32_t)f2bf(v[6]) | ((uint32_t)f2bf(v[7]) << 16);
    return u;
}

// async global->LDS, 16B per lane (LDS dest is lane-linear; global src is
// per-lane and may be permuted -> XOR-swizzle is applied on the GLOBAL side)
typedef __attribute__((address_space(1))) const void* gaddr_t;
typedef __attribute__((address_space(3))) void* laddr_t;
__device__ inline void gload_lds16(const void* g, void* l) {
    __builtin_amdgcn_global_load_lds((gaddr_t)g, (laddr_t)l, 16, 0, 0);
}

// XCD-aware tile swizzle (requires gridDim.y % 8 == 0)
__device__ inline void swizzle_tiles(int& tr, int& tc) {
    const int cx = gridDim.x, cy = gridDim.y;
    const int id = blockIdx.y * cx + blockIdx.x;
    const int k = id & 7;
    const int q = id >> 3;
    tr = k * (cy >> 3) + q / cx;
    tc = q % cx;
}

// ---------------------------------------------------------------------------
// Reduction helpers (256-thread blocks, wave64)
// ---------------------------------------------------------------------------
__device__ inline float wave_sum(float v) {
#pragma unroll
    for (int off = 32; off > 0; off >>= 1) v += __shfl_down(v, off, 64);
    return v;
}
__device__ inline float block_sum256(float v, float* sm) {
    v = wave_sum(v);
    const int w = threadIdx.x >> 6;
    if ((threadIdx.x & 63) == 0) sm[w] = v;
    __syncthreads();
    const float r = sm[0] + sm[1] + sm[2] + sm[3];
    __syncthreads();
    return r;
}

// ---------------------------------------------------------------------------
// f32 -> bf16 flat convert, 8 elems/thread
// ---------------------------------------------------------------------------
__global__ __launch_bounds__(256) void f2bf_kernel(
    const float* __restrict__ in, u16* __restrict__ out, int n) {
    const int i = (blockIdx.x * 256 + threadIdx.x) * 8;
    if (i + 7 >= n) {
        for (int j = i; j < n; ++j) out[j] = f2bf(in[j]);
        return;
    }
    const float4 a = *(const float4*)(in + i);
    const float4 b = *(const float4*)(in + i + 4);
    float v[8] = {a.x, a.y, a.z, a.w, b.x, b.y, b.z, b.w};
    *(uint4*)(out + i) = pack8(v);
}

// ---------------------------------------------------------------------------
// Fused prep: f32 (R,C) -> bf16 (R,C) copy + bf16 (C,R) transpose +
// csq[c] += (1/R) sum_r v^2.  grid (C/32, R/32), block 256.
// ---------------------------------------------------------------------------
__global__ __launch_bounds__(256) void prep_kernel(
    const float* __restrict__ in, u16* __restrict__ outN,
    u16* __restrict__ outT, float* __restrict__ csq, int R, int C,
    float inv_R) {
    __shared__ float tile[32][33];
    __shared__ float sred[8][32];
    const int bx = blockIdx.x * 32, by = blockIdx.y * 32;
    const int x = threadIdx.x & 31, y0 = threadIdx.x >> 5;
    float s = 0.f;
#pragma unroll
    for (int yy = 0; yy < 32; yy += 8) {
        const float v = in[(size_t)(by + y0 + yy) * C + bx + x];
        tile[y0 + yy][x] = v;
        outN[(size_t)(by + y0 + yy) * C + bx + x] = f2bf(v);
        s = fmaf(v, v, s);
    }
    sred[y0][x] = s;
    __syncthreads();
#pragma unroll
    for (int yy = 0; yy < 32; yy += 8)
        outT[(size_t)(bx + y0 + yy) * R + by + x] = f2bf(tile[x][y0 + yy]);
    if (y0 == 0) {
        float t = 0.f;
#pragma unroll
        for (int k2 = 0; k2 < 8; ++k2) t += sred[k2][x];
        atomicAdd(csq + bx + x, t * inv_R);
    }
}

// ---------------------------------------------------------------------------
// MFMA bf16 GEMM, 256x128 tile, 512 threads (R5-PROVEN, encode/decode):
// u = exp(alpha*acc - bias[col]) -> bf16 C; Saux[row] += row-sum.
// R9 NaN post-mortem: the write-out loop was mangled in the revert (u<4
// wrote only half the columns -> half of e_bf stale -> NaN). Restored to
// R5's exact u<8 loop. 8 waves (4 row-bands x 2 col-halves), 64x64
// out/wave (acc[4][4]); measured 51us, VGPR 60 + 64 AGPR, zero spill.
// ---------------------------------------------------------------------------
__global__ __launch_bounds__(512, 2) void mfma_big_kernel(
    const u16* __restrict__ A, const u16* __restrict__ Bm,
    u16* __restrict__ C, const float* __restrict__ bias,
    float* __restrict__ Saux, int M, int N, int Kd, float alpha) {
    __shared__ u16 smem[32768];  // loop: As 16384 u16 | Bs 8192 u16; epi: all
    u16* As = smem;
    u16* Bs = smem + 16384;
    const int tid = threadIdx.x;
    int btr, btc;
    swizzle_tiles(btr, btc);
    const int row0 = btr * 256, col0 = btc * 128;
    const int lane = tid & 63, wave = tid >> 6;
    const int wr = wave >> 1, wc = wave & 1;  // row-band (0..3), col-half
    const int tx = lane & 15, quad = lane >> 4;
    const int txl = tx & 7;

    f32x4 acc[4][4] = {};

    for (int k0 = 0; k0 < Kd; k0 += 64) {
#pragma unroll
        for (int l = 0; l < 4; ++l) {
            const int lin = l * 4096 + tid * 8;
            const int r = lin >> 6;
            const int c = (((lin >> 3) & 7) ^ (r & 7)) * 8;  // XOR-swizzled src
            gload_lds16(A + (size_t)(row0 + r) * Kd + k0 + c, &As[lin]);
        }
#pragma unroll
        for (int l = 0; l < 2; ++l) {
            const int lin = l * 4096 + tid * 8;
            const int r = lin >> 6;
            const int c = (((lin >> 3) & 7) ^ (r & 7)) * 8;
            gload_lds16(Bm + (size_t)(col0 + r) * Kd + k0 + c, &Bs[lin]);
        }
        __syncthreads();
#pragma unroll
        for (int ks = 0; ks < 2; ++ks) {
            bf16x8 af[4], bfr[4];
            const int gsw = ((ks * 4 + quad) ^ txl) * 8;
#pragma unroll
            for (int i = 0; i < 4; ++i)
                af[i] = *(const bf16x8*)&As[(wr * 64 + i * 16 + tx) * 64 + gsw];
#pragma unroll
            for (int j = 0; j < 4; ++j)
                bfr[j] = *(const bf16x8*)&Bs[(wc * 64 + j * 16 + tx) * 64 + gsw];
#pragma unroll
            for (int i = 0; i < 4; ++i)
#pragma unroll
                for (int j = 0; j < 4; ++j)
                    acc[i][j] = __builtin_amdgcn_mfma_f32_16x16x32_bf16(
                        af[i], bfr[j], acc[i][j], 0, 0, 0);
        }
        __syncthreads();
    }

    // ---- epilogue: per-wave 64x64 patch at wave*4096 in LDS ----
    const int wbase = wave * 4096;
#pragma unroll
    for (int i = 0; i < 4; ++i) {
        float srow[4] = {0.f, 0.f, 0.f, 0.f};
#pragma unroll
        for (int j = 0; j < 4; ++j) {
            const int pcol = j * 16 + tx;
            const float cb = bias[col0 + wc * 64 + pcol];
#pragma unroll
            for (int r = 0; r < 4; ++r) {
                const int prow = i * 16 + quad * 4 + r;  // in-wave row 0..63
                const int paddr = wbase + prow * 64 +
                    (((pcol >> 3) ^ (prow & 7)) << 3) + (pcol & 7);
                const float v = __expf(fmaf(acc[i][j][r], alpha, -cb));
                srow[r] += v;
                smem[paddr] = f2bf(v);
            }
        }
#pragma unroll
        for (int r = 0; r < 4; ++r) {
            float s = srow[r];
            s += __shfl_xor(s, 1, 64);
            s += __shfl_xor(s, 2, 64);
            s += __shfl_xor(s, 4, 64);
            s += __shfl_xor(s, 8, 64);
            if (tx == 0)
                atomicAdd(&Saux[row0 + wr * 64 + i * 16 + quad * 4 + r], s);
        }
    }
    __syncthreads();

    // ---- write-out: row rr=tid>>1 (0..255), half hs (64 cols), coalesced ----
    const int rr = tid >> 1, hs = tid & 1;
#pragma unroll
    for (int u = 0; u < 8; ++u) {
        const int c = hs * 64 + u * 8;
        const int wv = (rr >> 6) * 2 + (c >> 6);  // source wave patch
        const int rl = rr & 63, cl = c & 63;
        const int pg = ((cl >> 3) ^ (rl & 7)) << 3;
        *(uint4*)(C + (size_t)(row0 + rr) * N + col0 + c) =
            *(const uint4*)&smem[wv * 4096 + rl * 64 + pg];
    }
}

// ---------------------------------------------------------------------------
// MFMA bf16 GEMM, 256x128 tile (proven R5 geometry + divide epilogue):
// z0 = (e @ xb^T) / S_enc[row]. Ingest 192MB -> 96MB vs 128x64.
// Epilogue writes acc directly per-lane (no LDS round-trip).
// ---------------------------------------------------------------------------
__global__ __launch_bounds__(512, 2) void mfma_zdiv_kernel(
    const u16* __restrict__ A, const u16* __restrict__ Bm,
    u16* __restrict__ C, const float* __restrict__ Srow,
    int M, int N, int Kd) {
    __shared__ u16 As[256 * 64];
    __shared__ u16 Bs[128 * 64];
    const int tid = threadIdx.x;
    int btr, btc;
    swizzle_tiles(btr, btc);
    const int row0 = btr * 256, col0 = btc * 128;
    const int lane = tid & 63, wave = tid >> 6;
    const int wr = wave >> 1, wc = wave & 1;
    const int tx = lane & 15, quad = lane >> 4;
    const int txl = tx & 7;

    f32x4 acc[4][4] = {};

    for (int k0 = 0; k0 < Kd; k0 += 64) {
#pragma unroll
        for (int l = 0; l < 4; ++l) {
            const int lin = l * 4096 + tid * 8;
            const int r = lin >> 6;
            const int c = (((lin >> 3) & 7) ^ (r & 7)) * 8;
            gload_lds16(A + (size_t)(row0 + r) * Kd + k0 + c, &As[lin]);
        }
#pragma unroll
        for (int l = 0; l < 2; ++l) {
            const int lin = l * 4096 + tid * 8;
            const int r = lin >> 6;
            const int c = (((lin >> 3) & 7) ^ (r & 7)) * 8;
            gload_lds16(Bm + (size_t)(col0 + r) * Kd + k0 + c, &Bs[lin]);
        }
        __syncthreads();
#pragma unroll
        for (int ks = 0; ks < 2; ++ks) {
            bf16x8 af[4], bfr[4];
            const int gsw = ((ks * 4 + quad) ^ txl) * 8;
#pragma unroll
            for (int i = 0; i < 4; ++i)
                af[i] = *(const bf16x8*)&As[(wr * 64 + i * 16 + tx) * 64 + gsw];
#pragma unroll
            for (int j = 0; j < 4; ++j)
                bfr[j] = *(const bf16x8*)&Bs[(wc * 64 + j * 16 + tx) * 64 + gsw];
#pragma unroll
            for (int i = 0; i < 4; ++i)
#pragma unroll
                for (int j = 0; j < 4; ++j)
                    acc[i][j] = __builtin_amdgcn_mfma_f32_16x16x32_bf16(
                        af[i], bfr[j], acc[i][j], 0, 0, 0);
        }
        __syncthreads();
    }

#pragma unroll
    for (int i = 0; i < 4; ++i)
#pragma unroll
        for (int r = 0; r < 4; ++r) {
            const int row = row0 + wr * 64 + i * 16 + quad * 4 + r;
            const float sc = 1.0f / Srow[row];
#pragma unroll
            for (int j = 0; j < 4; ++j) {
                const int col = col0 + wc * 64 + j * 16 + tx;
                C[(size_t)row * N + col] = f2bf(acc[i][j][r] * sc);
            }
        }
}

// ---------------------------------------------------------------------------
// STEP (R4 structure, kept): K-split partial kernel. 128 rows/block x P=4
// K-parts -> grid 256 (1/CU). Blocks write f32 z' partials Zp[4][B][E] +
// Sw partials Sp[4][B]; norm_kernel sums parts, divides, writes z bf16.
// ---------------------------------------------------------------------------
constexpr int XBTS0 = 0;          // [32k][256e] granule-XOR8
constexpr int XBTS1 = 8192;
constexpr int XBS0 = 16384;       // [256e][32k] granule-XOR4 (involution)
constexpr int XBS1 = 24576;
constexpr int ES0 = 32768;        // [128r][40k-padded]
constexpr int ES1 = 37888;
constexpr int WSO = 43008;        // [128r][40k-padded]
constexpr int SMEM_U16 = 48128;

__global__ __launch_bounds__(512, 2) void step_part_kernel(
    const u16* __restrict__ Z,      // (B,E) current z
    const u16* __restrict__ XbT,    // (K,E)
    const u16* __restrict__ Xb,     // (E,K)
    const u16* __restrict__ Ebf,    // (B,K) unnormalized encode weights
    const float* __restrict__ c2b,  // (K)
    float* __restrict__ Zp,         // (4,B,E) f32 partials
    float* __restrict__ Sp) {       // (4,B) f32 partials
    __shared__ u16 smem[SMEM_U16];
    __shared__ float redS[2][128];
    const int tid = threadIdx.x;
    const int lane = tid & 63, wave = tid >> 6;
    const int wh = wave >> 1, wk = wave & 1;  // 32-row band, k/e-half
    const int tx = lane & 15, quad = lane >> 4;
    const int part = blockIdx.x & 3;
    const int row0 = (blockIdx.x >> 2) * 128;
    const int kbase = part * 512;
    const float ascale = 2.0f / (float)E;
    const int kcol = wk * 16 + tx;            // lane's k-col in chunk (0..31)
    const int erow_ = tid >> 2;               // e stage: row (0..127)
    const int eg_ = tid & 3;                  // e stage: 8-col group
    const int ewaddr = erow_ * 40 + eg_ * 8;  // padded es/ws row stride 40 u16

    // ---- prologue: z band -> region A ([128r][256e], granule-XOR8) ----
#pragma unroll
    for (int l = 0; l < 8; ++l) {
        const int lin = l * 4096 + tid * 8;
        const int r = lin >> 8, gf = (lin >> 3) & 31;
        const int eoff = ((gf & 24) | ((gf & 7) ^ (r & 7))) << 3;
        gload_lds16(Z + (size_t)(row0 + r) * E + eoff, &smem[lin]);
    }
    // e chunk 0 -> regs ; cb
    uint4 ereg = *(const uint4*)&Ebf[(size_t)(row0 + erow_) * K + kbase + eg_ * 8];
    float cb = c2b[kbase + kcol];
    WAIT_VM0;
    SCHED0;
    S_BARRIER;
    SCHED0;

    // z A-frags: af[i][s] = z[wh*32+i*16+tx][e = s*32+quad*8 ..]
    bf16x8 af[2][8];
#pragma unroll
    for (int i = 0; i < 2; ++i) {
        const int row = wh * 32 + i * 16 + tx;
#pragma unroll
        for (int s = 0; s < 8; ++s) {
            const int g = s * 4 + quad;
            const int gp = (g & 24) | ((g & 7) ^ (row & 7));
            af[i][s] = *(const bf16x8*)&smem[row * 256 + gp * 8];
        }
    }
    // es[0] write (region separate from A)
    *(uint4*)&smem[ES0 + ewaddr] = ereg;
    WAIT_LGKM0;  // af reads + es0 write done before region A is overwritten
    SCHED0;
    S_BARRIER;
    SCHED0;

    // stage chunk 0 into buffers 0
#pragma unroll
    for (int l = 0; l < 2; ++l) {
        const int lin = l * 4096 + tid * 8;
        const int r = lin >> 8, gf = (lin >> 3) & 31;
        const int eoff = ((gf & 24) | ((gf & 7) ^ (r & 7))) << 3;
        gload_lds16(XbT + (size_t)(kbase + r) * E + eoff, &smem[XBTS0 + lin]);
    }
#pragma unroll
    for (int l = 0; l < 2; ++l) {
        const int lin = l * 4096 + tid * 8;
        const int e = lin >> 5, gq = (lin >> 3) & 3;
        const int koff = (gq ^ (e & 3) ^ ((e >> 2) & 3)) << 3;
        gload_lds16(Xb + (size_t)e * K + kbase + koff, &smem[XBS0 + lin]);
    }
    WAIT_VM0;
    SCHED0;
    S_BARRIER;
    SCHED0;

    f32x4 acc2[2][8] = {};  // z' partial acc: [row-half i][e-frag f]
    float srow[2][4] = {};  // Sw partials

    for (int kc = 0; kc < 16; ++kc) {
        const int p = kc & 1;
        const int xbtsP = p ? XBTS1 : XBTS0;
        const int xbsP = p ? XBS1 : XBS0;
        float cbn = 0.f;
        // ---- 1. stage chunk kc+1 (4 gload_lds) + e kc+1 (reg) ----
        if (kc < 15) {
            const int kn0 = kbase + (kc + 1) * 32;
            const int xbtsN = p ? XBTS0 : XBTS1;
            const int xbsN = p ? XBS0 : XBS1;
#pragma unroll
            for (int l = 0; l < 2; ++l) {
                const int lin = l * 4096 + tid * 8;
                const int r = lin >> 8, gf = (lin >> 3) & 31;
                const int eoff = ((gf & 24) | ((gf & 7) ^ (r & 7))) << 3;
                gload_lds16(XbT + (size_t)(kn0 + r) * E + eoff,
                            &smem[xbtsN + lin]);
            }
#pragma unroll
            for (int l = 0; l < 2; ++l) {
                const int lin = l * 4096 + tid * 8;
                const int e = lin >> 5, gq = (lin >> 3) & 3;
                const int koff = (gq ^ (e & 3) ^ ((e >> 2) & 3)) << 3;
                gload_lds16(Xb + (size_t)e * K + kn0 + koff,
                            &smem[xbsN + lin]);
            }
            ereg = *(const uint4*)&Ebf[(size_t)(row0 + erow_) * K + kn0 + eg_ * 8];
            cbn = c2b[kn0 + kcol];
        }
        SCHED0;  // pin stage issue above compute

        // ---- 2. t-part: ta[i] = z(band rows) @ xbT(k-col = kcol) ----
        bf16x8 bfr[8];
#pragma unroll
        for (int s = 0; s < 8; ++s) {
            const int g = s * 4 + quad;
            const int gp = (g & 24) | ((g & 7) ^ (kcol & 7));
            bfr[s] = *(const bf16x8*)&smem[xbtsP + kcol * 256 + gp * 8];
        }
        f32x4 ta[2] = {};
#pragma unroll
        for (int s = 0; s < 8; ++s)
#pragma unroll
            for (int i = 0; i < 2; ++i)
                ta[i] = __builtin_amdgcn_mfma_f32_16x16x32_bf16(
                    af[i][s], bfr[s], ta[i], 0, 0, 0);

        // ---- 3. epilogue: w = e * exp(t*ascale - cb) -> ws; Sw partial ----
        const int esP = p ? ES1 : ES0;
#pragma unroll
        for (int i = 0; i < 2; ++i)
#pragma unroll
            for (int r = 0; r < 4; ++r) {
                const int prow = wh * 32 + i * 16 + quad * 4 + r;
                const int paddr = prow * 40 + kcol;
                const float ev = bf2f(smem[esP + paddr]);
                const float wv = ev * __expf(fmaf(ta[i][r], ascale, -cb));
                srow[i][r] += wv;
                smem[WSO + paddr] = f2bf(wv);
            }
        // ---- B1: ws visible cross-wave (k-halves); vm loads in flight ----
        WAIT_LGKM0;
        SCHED0;
        S_BARRIER;
        SCHED0;

        // ---- 4. z-part: acc2 += w(band, 32k) @ xbT(32k, e=wk*128..) ----
        bf16x8 a2[2];
#pragma unroll
        for (int i = 0; i < 2; ++i) {
            const int row = wh * 32 + i * 16 + tx;
            a2[i] = *(const bf16x8*)&smem[WSO + row * 40 + quad * 8];
        }
#pragma unroll
        for (int f = 0; f < 8; ++f) {
            const int ecol = wk * 128 + f * 16 + tx;
            const int gq = quad ^ (ecol & 3) ^ ((ecol >> 2) & 3);
            const bf16x8 b2 = *(const bf16x8*)&smem[xbsP + ecol * 32 + gq * 8];
#pragma unroll
            for (int i = 0; i < 2; ++i)
                acc2[i][f] = __builtin_amdgcn_mfma_f32_16x16x32_bf16(
                    a2[i], b2, acc2[i][f], 0, 0, 0);
        }
        // ---- 5. es(kc+1) write (compiler waits vmcnt for ereg) ----
        if (kc < 15) {
            const int esN = p ? ES0 : ES1;
            *(uint4*)&smem[esN + ewaddr] = ereg;
        }
        cb = cbn;
        // ---- B2: chunk kc+1 staged + es write visible; dbuf swap safe ----
        WAIT_LGKM0;
        SCHED0;
        WAIT_VM0;
        S_BARRIER;
        SCHED0;
    }

    // ---- Sw partials: reduce over tx, combine wk-halves via LDS ----
#pragma unroll
    for (int i = 0; i < 2; ++i)
#pragma unroll
        for (int r = 0; r < 4; ++r) {
            float s = srow[i][r];
            s += __shfl_xor(s, 1, 64);
            s += __shfl_xor(s, 2, 64);
            s += __shfl_xor(s, 4, 64);
            s += __shfl_xor(s, 8, 64);
            if (tx == 0) redS[wk][wh * 32 + i * 16 + quad * 4 + r] = s;
        }
    __syncthreads();
    if (tid < 128)
        Sp[(size_t)part * B + row0 + tid] = redS[0][tid] + redS[1][tid];

    // ---- Zp stores: f32 partials, coalesced in tx ----
#pragma unroll
    for (int i = 0; i < 2; ++i)
#pragma unroll
        for (int f = 0; f < 8; ++f)
#pragma unroll
            for (int r = 0; r < 4; ++r) {
                const int row = wh * 32 + i * 16 + quad * 4 + r;
                const int e = wk * 128 + f * 16 + tx;
                Zp[((size_t)part * B + row0 + row) * E + e] = acc2[i][f][r];
            }
}

// ---------------------------------------------------------------------------
// norm: z[row][e] = (sum_p Zp[p][row][e]) / (sum_p Sp[p][row]) -> bf16
// grid B*E/2048 = 1024, block 256, 8 elems/thread.
// ---------------------------------------------------------------------------
__global__ __launch_bounds__(256) void norm_kernel(
    const float* __restrict__ Zp, const float* __restrict__ Sp,
    u16* __restrict__ Z) {
    const int gidx = blockIdx.x * 256 + threadIdx.x;
    const int row = gidx >> 5;
    const int e0 = (gidx & 31) * 8;
    const float s = Sp[row] + Sp[B + row] + Sp[2 * B + row] + Sp[3 * B + row];
    const float inv = 1.0f / s;
    const size_t base = (size_t)row * E + e0;
    float4 a0 = *(const float4*)(Zp + base);
    float4 a1 = *(const float4*)(Zp + base + 4);
#pragma unroll
    for (int p = 1; p < 4; ++p) {
        const float4 b0 = *(const float4*)(Zp + (size_t)p * B * E + base);
        const float4 b1 = *(const float4*)(Zp + (size_t)p * B * E + base + 4);
        a0.x += b0.x; a0.y += b0.y; a0.z += b0.z; a0.w += b0.w;
        a1.x += b1.x; a1.y += b1.y; a1.z += b1.z; a1.w += b1.w;
    }
    float v[8] = {a0.x * inv, a0.y * inv, a0.z * inv, a0.w * inv,
                  a1.x * inv, a1.y * inv, a1.z * inv, a1.w * inv};
    *(uint4*)(Z + base) = pack8(v);
}

// ---------------------------------------------------------------------------
// MFMA bf16 GEMM, 256x128 tile (proven R5 geometry) with fused MSE-loss
// epilogue: D = P_NULL*exp(x2[row]) + S0[row];
// loss[row] += (1/N)*sum_col (acc/D - X[row,col])^2.  Ingest 512->384MB.
// ---------------------------------------------------------------------------
__global__ __launch_bounds__(512, 2) void mfma_loss_kernel(
    const u16* __restrict__ A, const u16* __restrict__ Bm,
    float* __restrict__ loss, const float* __restrict__ x2,
    const float* __restrict__ X, const float* __restrict__ S0,
    int M, int N, int Kd) {
    __shared__ u16 As[256 * 64];
    __shared__ u16 Bs[128 * 64];
    const int tid = threadIdx.x;
    int btr, btc;
    swizzle_tiles(btr, btc);
    const int row0 = btr * 256, col0 = btc * 128;
    const int lane = tid & 63, wave = tid >> 6;
    const int wr = (wave >> 1) * 64, wc = (wave & 1) * 64;
    const int tx = lane & 15, quad = lane >> 4;
    const int txl = tx & 7;

    f32x4 acc[4][4] = {};

    for (int k0 = 0; k0 < Kd; k0 += 64) {
#pragma unroll
        for (int l = 0; l < 4; ++l) {
            const int lin = l * 4096 + tid * 8;
            const int r = lin >> 6;
            const int c = (((lin >> 3) & 7) ^ (r & 7)) * 8;
            gload_lds16(A + (size_t)(row0 + r) * Kd + k0 + c, &As[lin]);
        }
#pragma unroll
        for (int l = 0; l < 2; ++l) {
            const int lin = l * 4096 + tid * 8;
            const int r = lin >> 6;
            const int c = (((lin >> 3) & 7) ^ (r & 7)) * 8;
            gload_lds16(Bm + (size_t)(col0 + r) * Kd + k0 + c, &Bs[lin]);
        }
        __syncthreads();
#pragma unroll
        for (int ks = 0; ks < 2; ++ks) {
            bf16x8 af[4], bfr[4];
            const int gsw = ((ks * 4 + quad) ^ txl) * 8;
#pragma unroll
            for (int i = 0; i < 4; ++i)
                af[i] = *(const bf16x8*)&As[(wr + i * 16 + tx) * 64 + gsw];
#pragma unroll
            for (int j = 0; j < 4; ++j)
                bfr[j] = *(const bf16x8*)&Bs[(wc + j * 16 + tx) * 64 + gsw];
#pragma unroll
            for (int i = 0; i < 4; ++i)
#pragma unroll
                for (int j = 0; j < 4; ++j)
                    acc[i][j] = __builtin_amdgcn_mfma_f32_16x16x32_bf16(
                        af[i], bfr[j], acc[i][j], 0, 0, 0);
        }
        __syncthreads();
    }

    const float inv_n = 1.0f / (float)N;
#pragma unroll
    for (int i = 0; i < 4; ++i) {
#pragma unroll
        for (int r = 0; r < 4; ++r) {
            const int row = row0 + wr + i * 16 + quad * 4 + r;
            const float D = P_NULL * __expf(x2[row]) + S0[row];
            const float invD = 1.0f / D;
            float s = 0.f;
#pragma unroll
            for (int j = 0; j < 4; ++j) {
                const int col = col0 + wc + j * 16 + tx;
                const float d = acc[i][j][r] * invD - X[(size_t)row * N + col];
                s = fmaf(d, d, s);
            }
            s += __shfl_xor(s, 1, 64);
            s += __shfl_xor(s, 2, 64);
            s += __shfl_xor(s, 4, 64);
            s += __shfl_xor(s, 8, 64);
            if (tx == 0) atomicAdd(&loss[row], s * inv_n);
        }
    }
}

// ---------------------------------------------------------------------------
// Row mean of squares of Z (B,E) bf16: x2[row] = mean(Z[row,:]^2)
// ---------------------------------------------------------------------------
__global__ __launch_bounds__(256) void rowmeansq_bf_kernel(
    const u16* __restrict__ Z, float* __restrict__ out) {
    __shared__ float sm[4];
    const float v = bf2f(Z[(size_t)blockIdx.x * E + threadIdx.x]);
    const float s = block_sum256(v * v, sm);
    if (threadIdx.x == 0) out[blockIdx.x] = s * (1.0f / (float)E);
}

// ---------------------------------------------------------------------------
extern "C" void kernel_launch(void* const* d_in, const int* in_sizes, int n_in,
                              void* d_out, int out_size, void* d_ws, size_t ws_size,
                              hipStream_t stream) {
    const float* images = (const float*)d_in[0];  // (B,G)
    const float* xa     = (const float*)d_in[1];  // (G,K)
    const float* xb     = (const float*)d_in[2];  // (E,K)
    float* out = (float*)d_out;                   // (B,)

    // workspace carve-up (u16 elements, all regions 16B-aligned)
    u16* img_bf = (u16*)d_ws;                      // B*G
    u16* xa_bf  = img_bf + (size_t)B * G;          // G*K
    u16* xaT_bf = xa_bf + (size_t)G * K;           // K*G
    u16* xb_bf  = xaT_bf + (size_t)K * G;          // E*K
    u16* xbT_bf = xb_bf + (size_t)E * K;           // K*E
    u16* e_bf   = xbT_bf + (size_t)K * E;          // B*K (unnormalized enc e)
    u16* wu_bf  = e_bf + (size_t)B * K;            // B*K (decode u)
    u16* z_bf   = wu_bf + (size_t)B * K;           // B*E
    float* c2a  = (float*)(z_bf + (size_t)B * E);  // K   --+ one memset
    float* c2b  = c2a + K;                         // K     |
    float* Svec = c2b + K;                         // 2*B --+ (S_enc, S0)
    float* x2z  = Svec + 2 * B;                    // B (fully written)
    float* Sp   = x2z + B;                         // 4*B (fully written/step)
    // Zp (4,B,E) f32 = 32MB overlays wu_bf (B*K u16 = 32MB; wu only used
    // in decode, after the step loop).
    float* Zp = (float*)wu_bf;

    (void)hipMemsetAsync(d_out, 0, (size_t)B * sizeof(float), stream);
    (void)hipMemsetAsync(c2a, 0, (size_t)(2 * K + 2 * B) * sizeof(float), stream);

    // prep: bf16 copies + transposes + column mean-squares (one read each)
    f2bf_kernel<<<(B * G) / 2048, 256, 0, stream>>>(images, img_bf, B * G);
    prep_kernel<<<dim3(K / 32, G / 32), 256, 0, stream>>>(
        xa, xa_bf, xaT_bf, c2a, G, K, 1.0f / (float)G);
    prep_kernel<<<dim3(K / 32, E / 32), 256, 0, stream>>>(
        xb, xb_bf, xbT_bf, c2b, E, K, 1.0f / (float)E);

    // encode (softmax eliminated): e = exp(images@xa*(2/G) - c2a), S_enc=rowsum
    float* S_enc = Svec;
    mfma_big_kernel<<<dim3(K / 128, B / 256), 512, 0, stream>>>(
        img_bf, xaT_bf, e_bf, c2a, S_enc, B, K, G, 2.0f / (float)G);

    // z0 = (e @ xb^T) / S_enc[row]   (== pik @ xb^T)
    mfma_zdiv_kernel<<<dim3(E / 128, B / 256), 512, 0, stream>>>(
        e_bf, xb_bf, z_bf, S_enc, B, E, K);

    // loop: K-split partial steps + normalize (w never hits HBM)
    for (int s = 0; s < N_STEP; ++s) {
        step_part_kernel<<<256, 512, 0, stream>>>(
            z_bf, xbT_bf, xb_bf, e_bf, c2b, Zp, Sp);
        norm_kernel<<<(B * E) / 2048, 256, 0, stream>>>(Zp, Sp, z_bf);
    }

    // decode: x2 = mean(z^2) ; u = exp(z@xb*(2/E) - c2b) ; S0 = rowsum(u)
    float* S0 = Svec + B;
    rowmeansq_bf_kernel<<<B, 256, 0, stream>>>(z_bf, x2z);
    mfma_big_kernel<<<dim3(K / 128, B / 256), 512, 0, stream>>>(
        z_bf, xbT_bf, wu_bf, c2b, S0, B, K, E, 2.0f / (float)E);

    // loss: recon = (u @ xa^T)/D[row], D = P_NULL*e^{x2}+S0 ;
    // loss[b] = mean_g (recon - images)^2
    mfma_loss_kernel<<<dim3(G / 128, B / 256), 512, 0, stream>>>(
        wu_bf, xa_bf, out, x2z, images, S0, B, G, K);
}

// Round 11
// 431.207 us; speedup vs baseline: 1.1391x; 1.0780x over previous
//
#include <hip/hip_runtime.h>
#include <hip/hip_bf16.h>

// Problem constants (match reference)
constexpr int B = 8192;
constexpr int G = 1024;
constexpr int E = 256;
constexpr int K = 2048;
constexpr float P_NULL = 0.1f;
constexpr int N_STEP = 4;

typedef unsigned short u16;
typedef short bf16x8 __attribute__((ext_vector_type(8)));
typedef float f32x4 __attribute__((ext_vector_type(4)));

// raw-sync primitives (step kernel pipelining)
#define S_BARRIER __builtin_amdgcn_s_barrier()
#define SCHED0 __builtin_amdgcn_sched_barrier(0)
#define WAIT_VM0 asm volatile("s_waitcnt vmcnt(0)" ::: "memory")
#define WAIT_LGKM0 asm volatile("s_waitcnt lgkmcnt(0)" ::: "memory")

// ---------------------------------------------------------------------------
// bf16 <-> f32 (RNE)
// ---------------------------------------------------------------------------
__device__ inline u16 f2bf(float f) {
    union { float f; uint32_t u; } cv;
    cv.f = f;
    const uint32_t u = cv.u;
    return (u16)((u + 0x7fffu + ((u >> 16) & 1u)) >> 16);
}
__device__ inline float bf2f(u16 h) {
    union { uint32_t u; float f; } cv;
    cv.u = ((uint32_t)h) << 16;
    return cv.f;
}
__device__ inline uint4 pack8(const float* v) {
    uint4 u;
    u.x = (uint32_t)f2bf(v[0]) | ((uint32_t)f2bf(v[1]) << 16);
    u.y = (uint32_t)f2bf(v[2]) | ((uint32_t)f2bf(v[3]) << 16);
    u.z = (uint32_t)f2bf(v[4]) | ((uint32_t)f2bf(v[5]) << 16);
    u.w = (uint32_t)f2bf(v[6]) | ((uint32_t)f2bf(v[7]) << 16);
    return u;
}

// async global->LDS, 16B per lane (LDS dest is lane-linear; global src is
// per-lane and may be permuted -> XOR-swizzle is applied on the GLOBAL side)
typedef __attribute__((address_space(1))) const void* gaddr_t;
typedef __attribute__((address_space(3))) void* laddr_t;
__device__ inline void gload_lds16(const void* g, void* l) {
    __builtin_amdgcn_global_load_lds((gaddr_t)g, (laddr_t)l, 16, 0, 0);
}

// XCD-aware tile swizzle (requires gridDim.y % 8 == 0)
__device__ inline void swizzle_tiles(int& tr, int& tc) {
    const int cx = gridDim.x, cy = gridDim.y;
    const int id = blockIdx.y * cx + blockIdx.x;
    const int k = id & 7;
    const int q = id >> 3;
    tr = k * (cy >> 3) + q / cx;
    tc = q % cx;
}

// ---------------------------------------------------------------------------
// Reduction helpers (256-thread blocks, wave64)
// ---------------------------------------------------------------------------
__device__ inline float wave_sum(float v) {
#pragma unroll
    for (int off = 32; off > 0; off >>= 1) v += __shfl_down(v, off, 64);
    return v;
}
__device__ inline float block_sum256(float v, float* sm) {
    v = wave_sum(v);
    const int w = threadIdx.x >> 6;
    if ((threadIdx.x & 63) == 0) sm[w] = v;
    __syncthreads();
    const float r = sm[0] + sm[1] + sm[2] + sm[3];
    __syncthreads();
    return r;
}

// ---------------------------------------------------------------------------
// f32 -> bf16 flat convert, 8 elems/thread
// ---------------------------------------------------------------------------
__global__ __launch_bounds__(256) void f2bf_kernel(
    const float* __restrict__ in, u16* __restrict__ out, int n) {
    const int i = (blockIdx.x * 256 + threadIdx.x) * 8;
    if (i + 7 >= n) {
        for (int j = i; j < n; ++j) out[j] = f2bf(in[j]);
        return;
    }
    const float4 a = *(const float4*)(in + i);
    const float4 b = *(const float4*)(in + i + 4);
    float v[8] = {a.x, a.y, a.z, a.w, b.x, b.y, b.z, b.w};
    *(uint4*)(out + i) = pack8(v);
}

// ---------------------------------------------------------------------------
// Fused prep: f32 (R,C) -> bf16 (R,C) copy + bf16 (C,R) transpose +
// csq[c] += (1/R) sum_r v^2.  grid (C/32, R/32), block 256.
// ---------------------------------------------------------------------------
__global__ __launch_bounds__(256) void prep_kernel(
    const float* __restrict__ in, u16* __restrict__ outN,
    u16* __restrict__ outT, float* __restrict__ csq, int R, int C,
    float inv_R) {
    __shared__ float tile[32][33];
    __shared__ float sred[8][32];
    const int bx = blockIdx.x * 32, by = blockIdx.y * 32;
    const int x = threadIdx.x & 31, y0 = threadIdx.x >> 5;
    float s = 0.f;
#pragma unroll
    for (int yy = 0; yy < 32; yy += 8) {
        const float v = in[(size_t)(by + y0 + yy) * C + bx + x];
        tile[y0 + yy][x] = v;
        outN[(size_t)(by + y0 + yy) * C + bx + x] = f2bf(v);
        s = fmaf(v, v, s);
    }
    sred[y0][x] = s;
    __syncthreads();
#pragma unroll
    for (int yy = 0; yy < 32; yy += 8)
        outT[(size_t)(bx + y0 + yy) * R + by + x] = f2bf(tile[x][y0 + yy]);
    if (y0 == 0) {
        float t = 0.f;
#pragma unroll
        for (int k2 = 0; k2 < 8; ++k2) t += sred[k2][x];
        atomicAdd(csq + bx + x, t * inv_R);
    }
}

// ---------------------------------------------------------------------------
// MFMA bf16 GEMM, 256x128 tile, 512 threads (R5-PROVEN, encode/decode):
// u = exp(alpha*acc - bias[col]) -> bf16 C; Saux[row] += row-sum.
// Measured 51us, VGPR 60 + 64 AGPR, zero spill (R5/R10).
// 8 waves (4 row-bands x 2 col-halves), 64x64 out/wave (acc[4][4]).
// ---------------------------------------------------------------------------
__global__ __launch_bounds__(512, 2) void mfma_big_kernel(
    const u16* __restrict__ A, const u16* __restrict__ Bm,
    u16* __restrict__ C, const float* __restrict__ bias,
    float* __restrict__ Saux, int M, int N, int Kd, float alpha) {
    __shared__ u16 smem[32768];  // loop: As 16384 u16 | Bs 8192 u16; epi: all
    u16* As = smem;
    u16* Bs = smem + 16384;
    const int tid = threadIdx.x;
    int btr, btc;
    swizzle_tiles(btr, btc);
    const int row0 = btr * 256, col0 = btc * 128;
    const int lane = tid & 63, wave = tid >> 6;
    const int wr = wave >> 1, wc = wave & 1;  // row-band (0..3), col-half
    const int tx = lane & 15, quad = lane >> 4;
    const int txl = tx & 7;

    f32x4 acc[4][4] = {};

    for (int k0 = 0; k0 < Kd; k0 += 64) {
#pragma unroll
        for (int l = 0; l < 4; ++l) {
            const int lin = l * 4096 + tid * 8;
            const int r = lin >> 6;
            const int c = (((lin >> 3) & 7) ^ (r & 7)) * 8;  // XOR-swizzled src
            gload_lds16(A + (size_t)(row0 + r) * Kd + k0 + c, &As[lin]);
        }
#pragma unroll
        for (int l = 0; l < 2; ++l) {
            const int lin = l * 4096 + tid * 8;
            const int r = lin >> 6;
            const int c = (((lin >> 3) & 7) ^ (r & 7)) * 8;
            gload_lds16(Bm + (size_t)(col0 + r) * Kd + k0 + c, &Bs[lin]);
        }
        __syncthreads();
#pragma unroll
        for (int ks = 0; ks < 2; ++ks) {
            bf16x8 af[4], bfr[4];
            const int gsw = ((ks * 4 + quad) ^ txl) * 8;
#pragma unroll
            for (int i = 0; i < 4; ++i)
                af[i] = *(const bf16x8*)&As[(wr * 64 + i * 16 + tx) * 64 + gsw];
#pragma unroll
            for (int j = 0; j < 4; ++j)
                bfr[j] = *(const bf16x8*)&Bs[(wc * 64 + j * 16 + tx) * 64 + gsw];
#pragma unroll
            for (int i = 0; i < 4; ++i)
#pragma unroll
                for (int j = 0; j < 4; ++j)
                    acc[i][j] = __builtin_amdgcn_mfma_f32_16x16x32_bf16(
                        af[i], bfr[j], acc[i][j], 0, 0, 0);
        }
        __syncthreads();
    }

    // ---- epilogue: per-wave 64x64 patch at wave*4096 in LDS ----
    const int wbase = wave * 4096;
#pragma unroll
    for (int i = 0; i < 4; ++i) {
        float srow[4] = {0.f, 0.f, 0.f, 0.f};
#pragma unroll
        for (int j = 0; j < 4; ++j) {
            const int pcol = j * 16 + tx;
            const float cb = bias[col0 + wc * 64 + pcol];
#pragma unroll
            for (int r = 0; r < 4; ++r) {
                const int prow = i * 16 + quad * 4 + r;  // in-wave row 0..63
                const int paddr = wbase + prow * 64 +
                    (((pcol >> 3) ^ (prow & 7)) << 3) + (pcol & 7);
                const float v = __expf(fmaf(acc[i][j][r], alpha, -cb));
                srow[r] += v;
                smem[paddr] = f2bf(v);
            }
        }
#pragma unroll
        for (int r = 0; r < 4; ++r) {
            float s = srow[r];
            s += __shfl_xor(s, 1, 64);
            s += __shfl_xor(s, 2, 64);
            s += __shfl_xor(s, 4, 64);
            s += __shfl_xor(s, 8, 64);
            if (tx == 0)
                atomicAdd(&Saux[row0 + wr * 64 + i * 16 + quad * 4 + r], s);
        }
    }
    __syncthreads();

    // ---- write-out: row rr=tid>>1 (0..255), half hs (64 cols), coalesced ----
    const int rr = tid >> 1, hs = tid & 1;
#pragma unroll
    for (int u = 0; u < 8; ++u) {
        const int c = hs * 64 + u * 8;
        const int wv = (rr >> 6) * 2 + (c >> 6);  // source wave patch
        const int rl = rr & 63, cl = c & 63;
        const int pg = ((cl >> 3) ^ (rl & 7)) << 3;
        *(uint4*)(C + (size_t)(row0 + rr) * N + col0 + c) =
            *(const uint4*)&smem[wv * 4096 + rl * 64 + pg];
    }
}

// ---------------------------------------------------------------------------
// MFMA bf16 GEMM, 64x64 tile, for z0 = (e @ xb^T) / S_enc[row].
// R10 post-mortem: 256x128 z0 had only 64 blocks (75% CUs idle) -> reverted
// to this R5-proven 64x64 (grid 256, ~25us).
// ---------------------------------------------------------------------------
__global__ __launch_bounds__(256) void mfma_z64_kernel(
    const u16* __restrict__ A, const u16* __restrict__ Bm,
    u16* __restrict__ C, const float* __restrict__ Srow,
    int M, int N, int Kd) {
    __shared__ u16 As[64 * 64];
    __shared__ u16 Bs[64 * 64];
    const int tid = threadIdx.x;
    int btr, btc;
    swizzle_tiles(btr, btc);
    const int row0 = btr * 64, col0 = btc * 64;
    const int lane = tid & 63, wave = tid >> 6;
    const int wr = (wave >> 1) * 32, wc = (wave & 1) * 32;
    const int tx = lane & 15, quad = lane >> 4;
    const int txl = tx & 7;

    f32x4 acc[2][2] = {};

    for (int k0 = 0; k0 < Kd; k0 += 64) {
#pragma unroll
        for (int l = 0; l < 2; ++l) {
            const int lin = l * 2048 + tid * 8;
            const int r = lin >> 6;
            const int c = (((lin >> 3) & 7) ^ (r & 7)) * 8;
            gload_lds16(A + (size_t)(row0 + r) * Kd + k0 + c, &As[lin]);
        }
#pragma unroll
        for (int l = 0; l < 2; ++l) {
            const int lin = l * 2048 + tid * 8;
            const int r = lin >> 6;
            const int c = (((lin >> 3) & 7) ^ (r & 7)) * 8;
            gload_lds16(Bm + (size_t)(col0 + r) * Kd + k0 + c, &Bs[lin]);
        }
        __syncthreads();
#pragma unroll
        for (int ks = 0; ks < 2; ++ks) {
            bf16x8 af[2], bfr[2];
            const int gsw = ((ks * 4 + quad) ^ txl) * 8;
#pragma unroll
            for (int i = 0; i < 2; ++i)
                af[i] = *(const bf16x8*)&As[(wr + i * 16 + tx) * 64 + gsw];
#pragma unroll
            for (int j = 0; j < 2; ++j)
                bfr[j] = *(const bf16x8*)&Bs[(wc + j * 16 + tx) * 64 + gsw];
#pragma unroll
            for (int i = 0; i < 2; ++i)
#pragma unroll
                for (int j = 0; j < 2; ++j)
                    acc[i][j] = __builtin_amdgcn_mfma_f32_16x16x32_bf16(
                        af[i], bfr[j], acc[i][j], 0, 0, 0);
        }
        __syncthreads();
    }

#pragma unroll
    for (int i = 0; i < 2; ++i)
#pragma unroll
        for (int r = 0; r < 4; ++r) {
            const int row = row0 + wr + i * 16 + quad * 4 + r;
            const float sc = Srow ? (1.0f / Srow[row]) : 1.0f;
#pragma unroll
            for (int j = 0; j < 2; ++j) {
                const int col = col0 + wc + j * 16 + tx;
                C[(size_t)row * N + col] = f2bf(acc[i][j][r] * sc);
            }
        }
}

// ---------------------------------------------------------------------------
// STEP (R4 structure, kept): K-split partial kernel. 128 rows/block x P=4
// K-parts -> grid 256 (1/CU). Blocks write f32 z' partials Zp[4][B][E] +
// Sw partials Sp[4][B]; norm_kernel sums parts, divides, writes z bf16.
// ---------------------------------------------------------------------------
constexpr int XBTS0 = 0;          // [32k][256e] granule-XOR8
constexpr int XBTS1 = 8192;
constexpr int XBS0 = 16384;       // [256e][32k] granule-XOR4 (involution)
constexpr int XBS1 = 24576;
constexpr int ES0 = 32768;        // [128r][40k-padded]
constexpr int ES1 = 37888;
constexpr int WSO = 43008;        // [128r][40k-padded]
constexpr int SMEM_U16 = 48128;

__global__ __launch_bounds__(512, 2) void step_part_kernel(
    const u16* __restrict__ Z,      // (B,E) current z
    const u16* __restrict__ XbT,    // (K,E)
    const u16* __restrict__ Xb,     // (E,K)
    const u16* __restrict__ Ebf,    // (B,K) unnormalized encode weights
    const float* __restrict__ c2b,  // (K)
    float* __restrict__ Zp,         // (4,B,E) f32 partials
    float* __restrict__ Sp) {       // (4,B) f32 partials
    __shared__ u16 smem[SMEM_U16];
    __shared__ float redS[2][128];
    const int tid = threadIdx.x;
    const int lane = tid & 63, wave = tid >> 6;
    const int wh = wave >> 1, wk = wave & 1;  // 32-row band, k/e-half
    const int tx = lane & 15, quad = lane >> 4;
    const int part = blockIdx.x & 3;
    const int row0 = (blockIdx.x >> 2) * 128;
    const int kbase = part * 512;
    const float ascale = 2.0f / (float)E;
    const int kcol = wk * 16 + tx;            // lane's k-col in chunk (0..31)
    const int erow_ = tid >> 2;               // e stage: row (0..127)
    const int eg_ = tid & 3;                  // e stage: 8-col group
    const int ewaddr = erow_ * 40 + eg_ * 8;  // padded es/ws row stride 40 u16

    // ---- prologue: z band -> region A ([128r][256e], granule-XOR8) ----
#pragma unroll
    for (int l = 0; l < 8; ++l) {
        const int lin = l * 4096 + tid * 8;
        const int r = lin >> 8, gf = (lin >> 3) & 31;
        const int eoff = ((gf & 24) | ((gf & 7) ^ (r & 7))) << 3;
        gload_lds16(Z + (size_t)(row0 + r) * E + eoff, &smem[lin]);
    }
    // e chunk 0 -> regs ; cb
    uint4 ereg = *(const uint4*)&Ebf[(size_t)(row0 + erow_) * K + kbase + eg_ * 8];
    float cb = c2b[kbase + kcol];
    WAIT_VM0;
    SCHED0;
    S_BARRIER;
    SCHED0;

    // z A-frags: af[i][s] = z[wh*32+i*16+tx][e = s*32+quad*8 ..]
    bf16x8 af[2][8];
#pragma unroll
    for (int i = 0; i < 2; ++i) {
        const int row = wh * 32 + i * 16 + tx;
#pragma unroll
        for (int s = 0; s < 8; ++s) {
            const int g = s * 4 + quad;
            const int gp = (g & 24) | ((g & 7) ^ (row & 7));
            af[i][s] = *(const bf16x8*)&smem[row * 256 + gp * 8];
        }
    }
    // es[0] write (region separate from A)
    *(uint4*)&smem[ES0 + ewaddr] = ereg;
    WAIT_LGKM0;  // af reads + es0 write done before region A is overwritten
    SCHED0;
    S_BARRIER;
    SCHED0;

    // stage chunk 0 into buffers 0
#pragma unroll
    for (int l = 0; l < 2; ++l) {
        const int lin = l * 4096 + tid * 8;
        const int r = lin >> 8, gf = (lin >> 3) & 31;
        const int eoff = ((gf & 24) | ((gf & 7) ^ (r & 7))) << 3;
        gload_lds16(XbT + (size_t)(kbase + r) * E + eoff, &smem[XBTS0 + lin]);
    }
#pragma unroll
    for (int l = 0; l < 2; ++l) {
        const int lin = l * 4096 + tid * 8;
        const int e = lin >> 5, gq = (lin >> 3) & 3;
        const int koff = (gq ^ (e & 3) ^ ((e >> 2) & 3)) << 3;
        gload_lds16(Xb + (size_t)e * K + kbase + koff, &smem[XBS0 + lin]);
    }
    WAIT_VM0;
    SCHED0;
    S_BARRIER;
    SCHED0;

    f32x4 acc2[2][8] = {};  // z' partial acc: [row-half i][e-frag f]
    float srow[2][4] = {};  // Sw partials

    for (int kc = 0; kc < 16; ++kc) {
        const int p = kc & 1;
        const int xbtsP = p ? XBTS1 : XBTS0;
        const int xbsP = p ? XBS1 : XBS0;
        float cbn = 0.f;
        // ---- 1. stage chunk kc+1 (4 gload_lds) + e kc+1 (reg) ----
        if (kc < 15) {
            const int kn0 = kbase + (kc + 1) * 32;
            const int xbtsN = p ? XBTS0 : XBTS1;
            const int xbsN = p ? XBS0 : XBS1;
#pragma unroll
            for (int l = 0; l < 2; ++l) {
                const int lin = l * 4096 + tid * 8;
                const int r = lin >> 8, gf = (lin >> 3) & 31;
                const int eoff = ((gf & 24) | ((gf & 7) ^ (r & 7))) << 3;
                gload_lds16(XbT + (size_t)(kn0 + r) * E + eoff,
                            &smem[xbtsN + lin]);
            }
#pragma unroll
            for (int l = 0; l < 2; ++l) {
                const int lin = l * 4096 + tid * 8;
                const int e = lin >> 5, gq = (lin >> 3) & 3;
                const int koff = (gq ^ (e & 3) ^ ((e >> 2) & 3)) << 3;
                gload_lds16(Xb + (size_t)e * K + kn0 + koff,
                            &smem[xbsN + lin]);
            }
            ereg = *(const uint4*)&Ebf[(size_t)(row0 + erow_) * K + kn0 + eg_ * 8];
            cbn = c2b[kn0 + kcol];
        }
        SCHED0;  // pin stage issue above compute

        // ---- 2. t-part: ta[i] = z(band rows) @ xbT(k-col = kcol) ----
        bf16x8 bfr[8];
#pragma unroll
        for (int s = 0; s < 8; ++s) {
            const int g = s * 4 + quad;
            const int gp = (g & 24) | ((g & 7) ^ (kcol & 7));
            bfr[s] = *(const bf16x8*)&smem[xbtsP + kcol * 256 + gp * 8];
        }
        f32x4 ta[2] = {};
#pragma unroll
        for (int s = 0; s < 8; ++s)
#pragma unroll
            for (int i = 0; i < 2; ++i)
                ta[i] = __builtin_amdgcn_mfma_f32_16x16x32_bf16(
                    af[i][s], bfr[s], ta[i], 0, 0, 0);

        // ---- 3. epilogue: w = e * exp(t*ascale - cb) -> ws; Sw partial ----
        const int esP = p ? ES1 : ES0;
#pragma unroll
        for (int i = 0; i < 2; ++i)
#pragma unroll
            for (int r = 0; r < 4; ++r) {
                const int prow = wh * 32 + i * 16 + quad * 4 + r;
                const int paddr = prow * 40 + kcol;
                const float ev = bf2f(smem[esP + paddr]);
                const float wv = ev * __expf(fmaf(ta[i][r], ascale, -cb));
                srow[i][r] += wv;
                smem[WSO + paddr] = f2bf(wv);
            }
        // ---- B1: ws visible cross-wave (k-halves); vm loads in flight ----
        WAIT_LGKM0;
        SCHED0;
        S_BARRIER;
        SCHED0;

        // ---- 4. z-part: acc2 += w(band, 32k) @ xbT(32k, e=wk*128..) ----
        bf16x8 a2[2];
#pragma unroll
        for (int i = 0; i < 2; ++i) {
            const int row = wh * 32 + i * 16 + tx;
            a2[i] = *(const bf16x8*)&smem[WSO + row * 40 + quad * 8];
        }
#pragma unroll
        for (int f = 0; f < 8; ++f) {
            const int ecol = wk * 128 + f * 16 + tx;
            const int gq = quad ^ (ecol & 3) ^ ((ecol >> 2) & 3);
            const bf16x8 b2 = *(const bf16x8*)&smem[xbsP + ecol * 32 + gq * 8];
#pragma unroll
            for (int i = 0; i < 2; ++i)
                acc2[i][f] = __builtin_amdgcn_mfma_f32_16x16x32_bf16(
                    a2[i], b2, acc2[i][f], 0, 0, 0);
        }
        // ---- 5. es(kc+1) write (compiler waits vmcnt for ereg) ----
        if (kc < 15) {
            const int esN = p ? ES0 : ES1;
            *(uint4*)&smem[esN + ewaddr] = ereg;
        }
        cb = cbn;
        // ---- B2: chunk kc+1 staged + es write visible; dbuf swap safe ----
        WAIT_LGKM0;
        SCHED0;
        WAIT_VM0;
        S_BARRIER;
        SCHED0;
    }

    // ---- Sw partials: reduce over tx, combine wk-halves via LDS ----
#pragma unroll
    for (int i = 0; i < 2; ++i)
#pragma unroll
        for (int r = 0; r < 4; ++r) {
            float s = srow[i][r];
            s += __shfl_xor(s, 1, 64);
            s += __shfl_xor(s, 2, 64);
            s += __shfl_xor(s, 4, 64);
            s += __shfl_xor(s, 8, 64);
            if (tx == 0) redS[wk][wh * 32 + i * 16 + quad * 4 + r] = s;
        }
    __syncthreads();
    if (tid < 128)
        Sp[(size_t)part * B + row0 + tid] = redS[0][tid] + redS[1][tid];

    // ---- Zp stores: f32 partials, coalesced in tx ----
#pragma unroll
    for (int i = 0; i < 2; ++i)
#pragma unroll
        for (int f = 0; f < 8; ++f)
#pragma unroll
            for (int r = 0; r < 4; ++r) {
                const int row = wh * 32 + i * 16 + quad * 4 + r;
                const int e = wk * 128 + f * 16 + tx;
                Zp[((size_t)part * B + row0 + row) * E + e] = acc2[i][f][r];
            }
}

// ---------------------------------------------------------------------------
// norm: z[row][e] = (sum_p Zp[p][row][e]) / (sum_p Sp[p][row]) -> bf16
// grid B*E/2048 = 1024, block 256, 8 elems/thread.
// ---------------------------------------------------------------------------
__global__ __launch_bounds__(256) void norm_kernel(
    const float* __restrict__ Zp, const float* __restrict__ Sp,
    u16* __restrict__ Z) {
    const int gidx = blockIdx.x * 256 + threadIdx.x;
    const int row = gidx >> 5;
    const int e0 = (gidx & 31) * 8;
    const float s = Sp[row] + Sp[B + row] + Sp[2 * B + row] + Sp[3 * B + row];
    const float inv = 1.0f / s;
    const size_t base = (size_t)row * E + e0;
    float4 a0 = *(const float4*)(Zp + base);
    float4 a1 = *(const float4*)(Zp + base + 4);
#pragma unroll
    for (int p = 1; p < 4; ++p) {
        const float4 b0 = *(const float4*)(Zp + (size_t)p * B * E + base);
        const float4 b1 = *(const float4*)(Zp + (size_t)p * B * E + base + 4);
        a0.x += b0.x; a0.y += b0.y; a0.z += b0.z; a0.w += b0.w;
        a1.x += b1.x; a1.y += b1.y; a1.z += b1.z; a1.w += b1.w;
    }
    float v[8] = {a0.x * inv, a0.y * inv, a0.z * inv, a0.w * inv,
                  a1.x * inv, a1.y * inv, a1.z * inv, a1.w * inv};
    *(uint4*)(Z + base) = pack8(v);
}

// ---------------------------------------------------------------------------
// MFMA bf16 GEMM (128x128 tile, R5-proven grid 512 blocks = 2/CU) with fused
// MSE-loss epilogue: D = P_NULL*exp(x2[row]) + S0[row];
// loss[row] += (1/N)*sum_col (acc/D - X[row,col])^2
// R11 change: X read as bf16 (img_bf) instead of f32 images — halves the
// 32MB epilogue stream; quantization error ~5e-4 after column averaging,
// well under the 2.39e-2 threshold.
// ---------------------------------------------------------------------------
__global__ __launch_bounds__(256) void mfma_loss_kernel(
    const u16* __restrict__ A, const u16* __restrict__ Bm,
    float* __restrict__ loss, const float* __restrict__ x2,
    const u16* __restrict__ X, const float* __restrict__ S0,
    int M, int N, int Kd) {
    __shared__ u16 As[128 * 64];
    __shared__ u16 Bs[128 * 64];
    const int tid = threadIdx.x;
    int btr, btc;
    swizzle_tiles(btr, btc);
    const int row0 = btr * 128, col0 = btc * 128;
    const int lane = tid & 63, wave = tid >> 6;
    const int wr = (wave >> 1) * 64, wc = (wave & 1) * 64;
    const int tx = lane & 15, quad = lane >> 4;
    const int txl = tx & 7;

    f32x4 acc[4][4] = {};

    for (int k0 = 0; k0 < Kd; k0 += 64) {
#pragma unroll
        for (int l = 0; l < 4; ++l) {
            const int lin = l * 2048 + tid * 8;
            const int r = lin >> 6;
            const int c = (((lin >> 3) & 7) ^ (r & 7)) * 8;
            gload_lds16(A + (size_t)(row0 + r) * Kd + k0 + c, &As[lin]);
        }
#pragma unroll
        for (int l = 0; l < 4; ++l) {
            const int lin = l * 2048 + tid * 8;
            const int r = lin >> 6;
            const int c = (((lin >> 3) & 7) ^ (r & 7)) * 8;
            gload_lds16(Bm + (size_t)(col0 + r) * Kd + k0 + c, &Bs[lin]);
        }
        __syncthreads();
#pragma unroll
        for (int ks = 0; ks < 2; ++ks) {
            bf16x8 af[4], bfr[4];
            const int gsw = ((ks * 4 + quad) ^ txl) * 8;
#pragma unroll
            for (int i = 0; i < 4; ++i)
                af[i] = *(const bf16x8*)&As[(wr + i * 16 + tx) * 64 + gsw];
#pragma unroll
            for (int j = 0; j < 4; ++j)
                bfr[j] = *(const bf16x8*)&Bs[(wc + j * 16 + tx) * 64 + gsw];
#pragma unroll
            for (int i = 0; i < 4; ++i)
#pragma unroll
                for (int j = 0; j < 4; ++j)
                    acc[i][j] = __builtin_amdgcn_mfma_f32_16x16x32_bf16(
                        af[i], bfr[j], acc[i][j], 0, 0, 0);
        }
        __syncthreads();
    }

    const float inv_n = 1.0f / (float)N;
#pragma unroll
    for (int i = 0; i < 4; ++i) {
#pragma unroll
        for (int r = 0; r < 4; ++r) {
            const int row = row0 + wr + i * 16 + quad * 4 + r;
            const float D = P_NULL * __expf(x2[row]) + S0[row];
            const float invD = 1.0f / D;
            float s = 0.f;
#pragma unroll
            for (int j = 0; j < 4; ++j) {
                const int col = col0 + wc + j * 16 + tx;
                const float d =
                    acc[i][j][r] * invD - bf2f(X[(size_t)row * N + col]);
                s = fmaf(d, d, s);
            }
            s += __shfl_xor(s, 1, 64);
            s += __shfl_xor(s, 2, 64);
            s += __shfl_xor(s, 4, 64);
            s += __shfl_xor(s, 8, 64);
            if (tx == 0) atomicAdd(&loss[row], s * inv_n);
        }
    }
}

// ---------------------------------------------------------------------------
// Row mean of squares of Z (B,E) bf16: x2[row] = mean(Z[row,:]^2)
// ---------------------------------------------------------------------------
__global__ __launch_bounds__(256) void rowmeansq_bf_kernel(
    const u16* __restrict__ Z, float* __restrict__ out) {
    __shared__ float sm[4];
    const float v = bf2f(Z[(size_t)blockIdx.x * E + threadIdx.x]);
    const float s = block_sum256(v * v, sm);
    if (threadIdx.x == 0) out[blockIdx.x] = s * (1.0f / (float)E);
}

// ---------------------------------------------------------------------------
extern "C" void kernel_launch(void* const* d_in, const int* in_sizes, int n_in,
                              void* d_out, int out_size, void* d_ws, size_t ws_size,
                              hipStream_t stream) {
    const float* images = (const float*)d_in[0];  // (B,G)
    const float* xa     = (const float*)d_in[1];  // (G,K)
    const float* xb     = (const float*)d_in[2];  // (E,K)
    float* out = (float*)d_out;                   // (B,)

    // workspace carve-up (u16 elements, all regions 16B-aligned)
    u16* img_bf = (u16*)d_ws;                      // B*G
    u16* xa_bf  = img_bf + (size_t)B * G;          // G*K
    u16* xaT_bf = xa_bf + (size_t)G * K;           // K*G
    u16* xb_bf  = xaT_bf + (size_t)K * G;          // E*K
    u16* xbT_bf = xb_bf + (size_t)E * K;           // K*E
    u16* e_bf   = xbT_bf + (size_t)K * E;          // B*K (unnormalized enc e)
    u16* wu_bf  = e_bf + (size_t)B * K;            // B*K (decode u)
    u16* z_bf   = wu_bf + (size_t)B * K;           // B*E
    float* c2a  = (float*)(z_bf + (size_t)B * E);  // K   --+ one memset
    float* c2b  = c2a + K;                         // K     |
    float* Svec = c2b + K;                         // 2*B --+ (S_enc, S0)
    float* x2z  = Svec + 2 * B;                    // B (fully written)
    float* Sp   = x2z + B;                         // 4*B (fully written/step)
    // Zp (4,B,E) f32 = 32MB overlays wu_bf (B*K u16 = 32MB; wu only used
    // in decode, after the step loop).
    float* Zp = (float*)wu_bf;

    (void)hipMemsetAsync(d_out, 0, (size_t)B * sizeof(float), stream);
    (void)hipMemsetAsync(c2a, 0, (size_t)(2 * K + 2 * B) * sizeof(float), stream);

    // prep: bf16 copies + transposes + column mean-squares (one read each)
    f2bf_kernel<<<(B * G) / 2048, 256, 0, stream>>>(images, img_bf, B * G);
    prep_kernel<<<dim3(K / 32, G / 32), 256, 0, stream>>>(
        xa, xa_bf, xaT_bf, c2a, G, K, 1.0f / (float)G);
    prep_kernel<<<dim3(K / 32, E / 32), 256, 0, stream>>>(
        xb, xb_bf, xbT_bf, c2b, E, K, 1.0f / (float)E);

    // encode (softmax eliminated): e = exp(images@xa*(2/G) - c2a), S_enc=rowsum
    float* S_enc = Svec;
    mfma_big_kernel<<<dim3(K / 128, B / 256), 512, 0, stream>>>(
        img_bf, xaT_bf, e_bf, c2a, S_enc, B, K, G, 2.0f / (float)G);

    // z0 = (e @ xb^T) / S_enc[row]   (== pik @ xb^T)
    mfma_z64_kernel<<<dim3(E / 64, B / 64), 256, 0, stream>>>(
        e_bf, xb_bf, z_bf, S_enc, B, E, K);

    // loop: K-split partial steps + normalize (w never hits HBM)
    for (int s = 0; s < N_STEP; ++s) {
        step_part_kernel<<<256, 512, 0, stream>>>(
            z_bf, xbT_bf, xb_bf, e_bf, c2b, Zp, Sp);
        norm_kernel<<<(B * E) / 2048, 256, 0, stream>>>(Zp, Sp, z_bf);
    }

    // decode: x2 = mean(z^2) ; u = exp(z@xb*(2/E) - c2b) ; S0 = rowsum(u)
    float* S0 = Svec + B;
    rowmeansq_bf_kernel<<<B, 256, 0, stream>>>(z_bf, x2z);
    mfma_big_kernel<<<dim3(K / 128, B / 256), 512, 0, stream>>>(
        z_bf, xbT_bf, wu_bf, c2b, S0, B, K, E, 2.0f / (float)E);

    // loss: recon = (u @ xa^T)/D[row], D = P_NULL*e^{x2}+S0 ;
    // loss[b] = mean_g (recon - images)^2  (X read as bf16 img_bf)
    mfma_loss_kernel<<<dim3(G / 128, B / 128), 256, 0, stream>>>(
        wu_bf, xa_bf, out, x2z, img_bf, S0, B, G, K);
}

// Round 12
// 419.883 us; speedup vs baseline: 1.1698x; 1.0270x over previous
//
#include <hip/hip_runtime.h>
#include <hip/hip_bf16.h>

// Problem constants (match reference)
constexpr int B = 8192;
constexpr int G = 1024;
constexpr int E = 256;
constexpr int K = 2048;
constexpr float P_NULL = 0.1f;
constexpr int N_STEP = 4;

typedef unsigned short u16;
typedef short bf16x8 __attribute__((ext_vector_type(8)));
typedef float f32x4 __attribute__((ext_vector_type(4)));

// raw-sync primitives (step kernel pipelining)
#define S_BARRIER __builtin_amdgcn_s_barrier()
#define SCHED0 __builtin_amdgcn_sched_barrier(0)
#define WAIT_VM0 asm volatile("s_waitcnt vmcnt(0)" ::: "memory")
#define WAIT_LGKM0 asm volatile("s_waitcnt lgkmcnt(0)" ::: "memory")

// ---------------------------------------------------------------------------
// bf16 <-> f32 (RNE)
// ---------------------------------------------------------------------------
__device__ inline u16 f2bf(float f) {
    union { float f; uint32_t u; } cv;
    cv.f = f;
    const uint32_t u = cv.u;
    return (u16)((u + 0x7fffu + ((u >> 16) & 1u)) >> 16);
}
__device__ inline float bf2f(u16 h) {
    union { uint32_t u; float f; } cv;
    cv.u = ((uint32_t)h) << 16;
    return cv.f;
}
__device__ inline uint4 pack8(const float* v) {
    uint4 u;
    u.x = (uint32_t)f2bf(v[0]) | ((uint32_t)f2bf(v[1]) << 16);
    u.y = (uint32_t)f2bf(v[2]) | ((uint32_t)f2bf(v[3]) << 16);
    u.z = (uint32_t)f2bf(v[4]) | ((uint32_t)f2bf(v[5]) << 16);
    u.w = (uint32_t)f2bf(v[6]) | ((uint32_t)f2bf(v[7]) << 16);
    return u;
}

// async global->LDS, 16B per lane (LDS dest is lane-linear; global src is
// per-lane and may be permuted -> XOR-swizzle is applied on the GLOBAL side)
typedef __attribute__((address_space(1))) const void* gaddr_t;
typedef __attribute__((address_space(3))) void* laddr_t;
__device__ inline void gload_lds16(const void* g, void* l) {
    __builtin_amdgcn_global_load_lds((gaddr_t)g, (laddr_t)l, 16, 0, 0);
}

// XCD-aware tile swizzle (requires gridDim.y % 8 == 0)
__device__ inline void swizzle_tiles(int& tr, int& tc) {
    const int cx = gridDim.x, cy = gridDim.y;
    const int id = blockIdx.y * cx + blockIdx.x;
    const int k = id & 7;
    const int q = id >> 3;
    tr = k * (cy >> 3) + q / cx;
    tc = q % cx;
}

// ---------------------------------------------------------------------------
// Reduction helpers (256-thread blocks, wave64)
// ---------------------------------------------------------------------------
__device__ inline float wave_sum(float v) {
#pragma unroll
    for (int off = 32; off > 0; off >>= 1) v += __shfl_down(v, off, 64);
    return v;
}
__device__ inline float block_sum256(float v, float* sm) {
    v = wave_sum(v);
    const int w = threadIdx.x >> 6;
    if ((threadIdx.x & 63) == 0) sm[w] = v;
    __syncthreads();
    const float r = sm[0] + sm[1] + sm[2] + sm[3];
    __syncthreads();
    return r;
}

// ---------------------------------------------------------------------------
// f32 -> bf16 flat convert, 8 elems/thread
// ---------------------------------------------------------------------------
__global__ __launch_bounds__(256) void f2bf_kernel(
    const float* __restrict__ in, u16* __restrict__ out, int n) {
    const int i = (blockIdx.x * 256 + threadIdx.x) * 8;
    if (i + 7 >= n) {
        for (int j = i; j < n; ++j) out[j] = f2bf(in[j]);
        return;
    }
    const float4 a = *(const float4*)(in + i);
    const float4 b = *(const float4*)(in + i + 4);
    float v[8] = {a.x, a.y, a.z, a.w, b.x, b.y, b.z, b.w};
    *(uint4*)(out + i) = pack8(v);
}

// ---------------------------------------------------------------------------
// Fused prep: f32 (R,C) -> bf16 (R,C) copy + bf16 (C,R) transpose +
// csq[c] += (1/R) sum_r v^2.  grid (C/32, R/32), block 256.
// ---------------------------------------------------------------------------
__global__ __launch_bounds__(256) void prep_kernel(
    const float* __restrict__ in, u16* __restrict__ outN,
    u16* __restrict__ outT, float* __restrict__ csq, int R, int C,
    float inv_R) {
    __shared__ float tile[32][33];
    __shared__ float sred[8][32];
    const int bx = blockIdx.x * 32, by = blockIdx.y * 32;
    const int x = threadIdx.x & 31, y0 = threadIdx.x >> 5;
    float s = 0.f;
#pragma unroll
    for (int yy = 0; yy < 32; yy += 8) {
        const float v = in[(size_t)(by + y0 + yy) * C + bx + x];
        tile[y0 + yy][x] = v;
        outN[(size_t)(by + y0 + yy) * C + bx + x] = f2bf(v);
        s = fmaf(v, v, s);
    }
    sred[y0][x] = s;
    __syncthreads();
#pragma unroll
    for (int yy = 0; yy < 32; yy += 8)
        outT[(size_t)(bx + y0 + yy) * R + by + x] = f2bf(tile[x][y0 + yy]);
    if (y0 == 0) {
        float t = 0.f;
#pragma unroll
        for (int k2 = 0; k2 < 8; ++k2) t += sred[k2][x];
        atomicAdd(csq + bx + x, t * inv_R);
    }
}

// ---------------------------------------------------------------------------
// MFMA bf16 GEMM, 256x128 tile, 512 threads (R5-PROVEN, encode/decode):
// u = exp(alpha*acc - bias[col]) -> bf16 C; Saux[row] += row-sum.
// Measured 50.5us, VGPR 60 + 64 AGPR, zero spill.
// 8 waves (4 row-bands x 2 col-halves), 64x64 out/wave (acc[4][4]).
// ---------------------------------------------------------------------------
__global__ __launch_bounds__(512, 2) void mfma_big_kernel(
    const u16* __restrict__ A, const u16* __restrict__ Bm,
    u16* __restrict__ C, const float* __restrict__ bias,
    float* __restrict__ Saux, int M, int N, int Kd, float alpha) {
    __shared__ u16 smem[32768];  // loop: As 16384 u16 | Bs 8192 u16; epi: all
    u16* As = smem;
    u16* Bs = smem + 16384;
    const int tid = threadIdx.x;
    int btr, btc;
    swizzle_tiles(btr, btc);
    const int row0 = btr * 256, col0 = btc * 128;
    const int lane = tid & 63, wave = tid >> 6;
    const int wr = wave >> 1, wc = wave & 1;  // row-band (0..3), col-half
    const int tx = lane & 15, quad = lane >> 4;
    const int txl = tx & 7;

    f32x4 acc[4][4] = {};

    for (int k0 = 0; k0 < Kd; k0 += 64) {
#pragma unroll
        for (int l = 0; l < 4; ++l) {
            const int lin = l * 4096 + tid * 8;
            const int r = lin >> 6;
            const int c = (((lin >> 3) & 7) ^ (r & 7)) * 8;  // XOR-swizzled src
            gload_lds16(A + (size_t)(row0 + r) * Kd + k0 + c, &As[lin]);
        }
#pragma unroll
        for (int l = 0; l < 2; ++l) {
            const int lin = l * 4096 + tid * 8;
            const int r = lin >> 6;
            const int c = (((lin >> 3) & 7) ^ (r & 7)) * 8;
            gload_lds16(Bm + (size_t)(col0 + r) * Kd + k0 + c, &Bs[lin]);
        }
        __syncthreads();
#pragma unroll
        for (int ks = 0; ks < 2; ++ks) {
            bf16x8 af[4], bfr[4];
            const int gsw = ((ks * 4 + quad) ^ txl) * 8;
#pragma unroll
            for (int i = 0; i < 4; ++i)
                af[i] = *(const bf16x8*)&As[(wr * 64 + i * 16 + tx) * 64 + gsw];
#pragma unroll
            for (int j = 0; j < 4; ++j)
                bfr[j] = *(const bf16x8*)&Bs[(wc * 64 + j * 16 + tx) * 64 + gsw];
#pragma unroll
            for (int i = 0; i < 4; ++i)
#pragma unroll
                for (int j = 0; j < 4; ++j)
                    acc[i][j] = __builtin_amdgcn_mfma_f32_16x16x32_bf16(
                        af[i], bfr[j], acc[i][j], 0, 0, 0);
        }
        __syncthreads();
    }

    // ---- epilogue: per-wave 64x64 patch at wave*4096 in LDS ----
    const int wbase = wave * 4096;
#pragma unroll
    for (int i = 0; i < 4; ++i) {
        float srow[4] = {0.f, 0.f, 0.f, 0.f};
#pragma unroll
        for (int j = 0; j < 4; ++j) {
            const int pcol = j * 16 + tx;
            const float cb = bias[col0 + wc * 64 + pcol];
#pragma unroll
            for (int r = 0; r < 4; ++r) {
                const int prow = i * 16 + quad * 4 + r;  // in-wave row 0..63
                const int paddr = wbase + prow * 64 +
                    (((pcol >> 3) ^ (prow & 7)) << 3) + (pcol & 7);
                const float v = __expf(fmaf(acc[i][j][r], alpha, -cb));
                srow[r] += v;
                smem[paddr] = f2bf(v);
            }
        }
#pragma unroll
        for (int r = 0; r < 4; ++r) {
            float s = srow[r];
            s += __shfl_xor(s, 1, 64);
            s += __shfl_xor(s, 2, 64);
            s += __shfl_xor(s, 4, 64);
            s += __shfl_xor(s, 8, 64);
            if (tx == 0)
                atomicAdd(&Saux[row0 + wr * 64 + i * 16 + quad * 4 + r], s);
        }
    }
    __syncthreads();

    // ---- write-out: row rr=tid>>1 (0..255), half hs (64 cols), coalesced ----
    const int rr = tid >> 1, hs = tid & 1;
#pragma unroll
    for (int u = 0; u < 8; ++u) {
        const int c = hs * 64 + u * 8;
        const int wv = (rr >> 6) * 2 + (c >> 6);  // source wave patch
        const int rl = rr & 63, cl = c & 63;
        const int pg = ((cl >> 3) ^ (rl & 7)) << 3;
        *(uint4*)(C + (size_t)(row0 + rr) * N + col0 + c) =
            *(const uint4*)&smem[wv * 4096 + rl * 64 + pg];
    }
}

// ---------------------------------------------------------------------------
// MFMA bf16 GEMM, 64x64 tile, for z0 = (e @ xb^T) / S_enc[row].
// ---------------------------------------------------------------------------
__global__ __launch_bounds__(256) void mfma_z64_kernel(
    const u16* __restrict__ A, const u16* __restrict__ Bm,
    u16* __restrict__ C, const float* __restrict__ Srow,
    int M, int N, int Kd) {
    __shared__ u16 As[64 * 64];
    __shared__ u16 Bs[64 * 64];
    const int tid = threadIdx.x;
    int btr, btc;
    swizzle_tiles(btr, btc);
    const int row0 = btr * 64, col0 = btc * 64;
    const int lane = tid & 63, wave = tid >> 6;
    const int wr = (wave >> 1) * 32, wc = (wave & 1) * 32;
    const int tx = lane & 15, quad = lane >> 4;
    const int txl = tx & 7;

    f32x4 acc[2][2] = {};

    for (int k0 = 0; k0 < Kd; k0 += 64) {
#pragma unroll
        for (int l = 0; l < 2; ++l) {
            const int lin = l * 2048 + tid * 8;
            const int r = lin >> 6;
            const int c = (((lin >> 3) & 7) ^ (r & 7)) * 8;
            gload_lds16(A + (size_t)(row0 + r) * Kd + k0 + c, &As[lin]);
        }
#pragma unroll
        for (int l = 0; l < 2; ++l) {
            const int lin = l * 2048 + tid * 8;
            const int r = lin >> 6;
            const int c = (((lin >> 3) & 7) ^ (r & 7)) * 8;
            gload_lds16(Bm + (size_t)(col0 + r) * Kd + k0 + c, &Bs[lin]);
        }
        __syncthreads();
#pragma unroll
        for (int ks = 0; ks < 2; ++ks) {
            bf16x8 af[2], bfr[2];
            const int gsw = ((ks * 4 + quad) ^ txl) * 8;
#pragma unroll
            for (int i = 0; i < 2; ++i)
                af[i] = *(const bf16x8*)&As[(wr + i * 16 + tx) * 64 + gsw];
#pragma unroll
            for (int j = 0; j < 2; ++j)
                bfr[j] = *(const bf16x8*)&Bs[(wc + j * 16 + tx) * 64 + gsw];
#pragma unroll
            for (int i = 0; i < 2; ++i)
#pragma unroll
                for (int j = 0; j < 2; ++j)
                    acc[i][j] = __builtin_amdgcn_mfma_f32_16x16x32_bf16(
                        af[i], bfr[j], acc[i][j], 0, 0, 0);
        }
        __syncthreads();
    }

#pragma unroll
    for (int i = 0; i < 2; ++i)
#pragma unroll
        for (int r = 0; r < 4; ++r) {
            const int row = row0 + wr + i * 16 + quad * 4 + r;
            const float sc = Srow ? (1.0f / Srow[row]) : 1.0f;
#pragma unroll
            for (int j = 0; j < 2; ++j) {
                const int col = col0 + wc + j * 16 + tx;
                C[(size_t)row * N + col] = f2bf(acc[i][j][r] * sc);
            }
        }
}

// ---------------------------------------------------------------------------
// STEP R12: K-split partials, 64 rows/block x P=4 -> grid 512 = 2 blocks/CU.
// R11 insight: encode (2 blk/CU) sustains ~15 B/cy/CU ingest; step (1 blk/CU,
// 94KB LDS) only 6.1 B/cy -> latency/barrier-bound, not ingest-bound. Fix:
// shrink the block so TWO fit per CU and let cross-block TLP hide the drains
// (the proven encode pattern). Single-buffered chunk staging, 3 barriers/chunk.
// 8 waves = 4 row-frags(16 rows) x 2 k/e-halves; per-wave af[8]+acc2[8] ~=
// 110 regs <= the 128 cap 4 waves/SIMD requires (launch_bounds(512,4)).
// LDS 42.5KB. Zp/Sp stay f32 P=4 (no precision change); norm unchanged.
// part = bid&3: round-robin XCD dispatch keeps ONE part per XCD (L2 locality).
// ---------------------------------------------------------------------------
constexpr int SXBT = 0;       // [32k][256e] granule-XOR8, 8192 u16
constexpr int SXB = 8192;     // [256e][32k] granule-XOR4, 8192 u16
constexpr int SES = 16384;    // [64r][36k-padded], 2304 u16
constexpr int SWS = 18688;    // [64r][36k-padded], 2304 u16
constexpr int SMEM_U16 = 20992;

__global__ __launch_bounds__(512, 4) void step_part_kernel(
    const u16* __restrict__ Z,      // (B,E) current z
    const u16* __restrict__ XbT,    // (K,E)
    const u16* __restrict__ Xb,     // (E,K)
    const u16* __restrict__ Ebf,    // (B,K) unnormalized encode weights
    const float* __restrict__ c2b,  // (K)
    float* __restrict__ Zp,         // (4,B,E) f32 partials
    float* __restrict__ Sp) {       // (4,B) f32 partials
    __shared__ u16 smem[SMEM_U16];
    __shared__ float redS[2][64];
    const int tid = threadIdx.x;
    const int lane = tid & 63, wave = tid >> 6;
    const int rf = wave >> 1, kf = wave & 1;  // row-frag(16), k/e-half
    const int tx = lane & 15, quad = lane >> 4;
    const int part = blockIdx.x & 3;
    const int row0 = (blockIdx.x >> 2) * 64;
    const int kbase = part * 512;
    const float ascale = 2.0f / (float)E;
    const int kcol = kf * 16 + tx;   // lane's k-col in chunk (0..31)
    const int erow_ = tid >> 3;      // e stage: row (0..63)
    const int eg_ = tid & 7;         // e stage: 4-col group
    const int ewaddr = erow_ * 36 + eg_ * 4;  // padded es/ws row stride 36

    // ---- prologue: z band [64][256] granule-XOR8 into smem[0..16384) ----
#pragma unroll
    for (int l = 0; l < 4; ++l) {
        const int lin = l * 4096 + tid * 8;
        const int r = lin >> 8, gf = (lin >> 3) & 31;
        const int eoff = ((gf & 24) | ((gf & 7) ^ (r & 7))) << 3;
        gload_lds16(Z + (size_t)(row0 + r) * E + eoff, &smem[lin]);
    }
    WAIT_VM0;
    SCHED0;
    S_BARRIER;
    SCHED0;

    // z A-frags for this wave's 16 rows: af[s], s covers E=256
    bf16x8 af[8];
    {
        const int arow = rf * 16 + tx;
#pragma unroll
        for (int s = 0; s < 8; ++s) {
            const int g = s * 4 + quad;
            const int gp = (g & 24) | ((g & 7) ^ (arow & 7));
            af[s] = *(const bf16x8*)&smem[arow * 256 + gp * 8];
        }
    }
    WAIT_LGKM0;  // af reads done before chunk staging overwrites region
    SCHED0;
    S_BARRIER;
    SCHED0;

    f32x4 acc2[8] = {};   // z' partial acc: [e-frag f] for rows rf*16..
    float srow[4] = {};   // Sw partials (this wave's rows x its kcols)

    for (int kc = 0; kc < 16; ++kc) {
        const int k0 = kbase + kc * 32;
        // ---- stage chunk (single-buffer; full drain; TLP hides) ----
#pragma unroll
        for (int l = 0; l < 2; ++l) {
            const int lin = l * 4096 + tid * 8;
            const int r = lin >> 8, gf = (lin >> 3) & 31;
            const int eoff = ((gf & 24) | ((gf & 7) ^ (r & 7))) << 3;
            gload_lds16(XbT + (size_t)(k0 + r) * E + eoff, &smem[SXBT + lin]);
        }
#pragma unroll
        for (int l = 0; l < 2; ++l) {
            const int lin = l * 4096 + tid * 8;
            const int e = lin >> 5, gq = (lin >> 3) & 3;
            const int koff = (gq ^ (e & 3) ^ ((e >> 2) & 3)) << 3;
            gload_lds16(Xb + (size_t)e * K + k0 + koff, &smem[SXB + lin]);
        }
        const uint2 ereg =
            *(const uint2*)&Ebf[(size_t)(row0 + erow_) * K + k0 + eg_ * 4];
        const float cb = c2b[k0 + kcol];
        SCHED0;
        WAIT_VM0;
        *(uint2*)&smem[SES + ewaddr] = ereg;
        WAIT_LGKM0;
        SCHED0;
        S_BARRIER;  // B0: chunk fully staged & visible
        SCHED0;

        // ---- t-part: ta = z(rows rf*16..) @ xbT(k-col = kcol) ----
        f32x4 ta = {};
#pragma unroll
        for (int s = 0; s < 8; ++s) {
            const int g = s * 4 + quad;
            const int gp = (g & 24) | ((g & 7) ^ (kcol & 7));
            const bf16x8 bfr = *(const bf16x8*)&smem[SXBT + kcol * 256 + gp * 8];
            ta = __builtin_amdgcn_mfma_f32_16x16x32_bf16(af[s], bfr, ta, 0, 0, 0);
        }

        // ---- epilogue: w = e * exp(t*ascale - cb) -> ws; Sw partial ----
#pragma unroll
        for (int r = 0; r < 4; ++r) {
            const int prow = rf * 16 + quad * 4 + r;
            const int pa = prow * 36 + kcol;
            const float ev = bf2f(smem[SES + pa]);
            const float wv = ev * __expf(fmaf(ta[r], ascale, -cb));
            srow[r] += wv;
            smem[SWS + pa] = f2bf(wv);
        }
        WAIT_LGKM0;
        SCHED0;
        S_BARRIER;  // B1: ws visible; xbts/es reads done
        SCHED0;

        // ---- z-part: acc2 += w(rows rf*16, 32k) @ xbT(32k, e=kf*128..) ----
        const bf16x8 a2 =
            *(const bf16x8*)&smem[SWS + (rf * 16 + tx) * 36 + quad * 8];
#pragma unroll
        for (int f = 0; f < 8; ++f) {
            const int ecol = kf * 128 + f * 16 + tx;
            const int gq = quad ^ (ecol & 3) ^ ((ecol >> 2) & 3);
            const bf16x8 b2 = *(const bf16x8*)&smem[SXB + ecol * 32 + gq * 8];
            acc2[f] = __builtin_amdgcn_mfma_f32_16x16x32_bf16(a2, b2, acc2[f],
                                                              0, 0, 0);
        }
        WAIT_LGKM0;
        SCHED0;
        S_BARRIER;  // B2: all LDS reads done -> next stage safe
        SCHED0;
    }

    // ---- Sw partials: reduce over tx, combine kf-halves via LDS ----
#pragma unroll
    for (int r = 0; r < 4; ++r) {
        float s = srow[r];
        s += __shfl_xor(s, 1, 64);
        s += __shfl_xor(s, 2, 64);
        s += __shfl_xor(s, 4, 64);
        s += __shfl_xor(s, 8, 64);
        if (tx == 0) redS[kf][rf * 16 + quad * 4 + r] = s;
    }
    __syncthreads();
    if (tid < 64)
        Sp[(size_t)part * B + row0 + tid] = redS[0][tid] + redS[1][tid];

    // ---- Zp stores: f32 partials, coalesced in tx (64B segments) ----
#pragma unroll
    for (int f = 0; f < 8; ++f)
#pragma unroll
        for (int r = 0; r < 4; ++r) {
            const int row = rf * 16 + quad * 4 + r;
            const int e = kf * 128 + f * 16 + tx;
            Zp[((size_t)part * B + row0 + row) * E + e] = acc2[f][r];
        }
}

// ---------------------------------------------------------------------------
// norm: z[row][e] = (sum_p Zp[p][row][e]) / (sum_p Sp[p][row]) -> bf16
// grid B*E/2048 = 1024, block 256, 8 elems/thread.
// ---------------------------------------------------------------------------
__global__ __launch_bounds__(256) void norm_kernel(
    const float* __restrict__ Zp, const float* __restrict__ Sp,
    u16* __restrict__ Z) {
    const int gidx = blockIdx.x * 256 + threadIdx.x;
    const int row = gidx >> 5;
    const int e0 = (gidx & 31) * 8;
    const float s = Sp[row] + Sp[B + row] + Sp[2 * B + row] + Sp[3 * B + row];
    const float inv = 1.0f / s;
    const size_t base = (size_t)row * E + e0;
    float4 a0 = *(const float4*)(Zp + base);
    float4 a1 = *(const float4*)(Zp + base + 4);
#pragma unroll
    for (int p = 1; p < 4; ++p) {
        const float4 b0 = *(const float4*)(Zp + (size_t)p * B * E + base);
        const float4 b1 = *(const float4*)(Zp + (size_t)p * B * E + base + 4);
        a0.x += b0.x; a0.y += b0.y; a0.z += b0.z; a0.w += b0.w;
        a1.x += b1.x; a1.y += b1.y; a1.z += b1.z; a1.w += b1.w;
    }
    float v[8] = {a0.x * inv, a0.y * inv, a0.z * inv, a0.w * inv,
                  a1.x * inv, a1.y * inv, a1.z * inv, a1.w * inv};
    *(uint4*)(Z + base) = pack8(v);
}

// ---------------------------------------------------------------------------
// MFMA bf16 GEMM (128x128 tile, 512 blocks = 2/CU) with fused MSE-loss
// epilogue: D = P_NULL*exp(x2[row]) + S0[row];
// loss[row] += (1/N)*sum_col (acc/D - X[row,col])^2   (X is bf16 img_bf)
// ---------------------------------------------------------------------------
__global__ __launch_bounds__(256) void mfma_loss_kernel(
    const u16* __restrict__ A, const u16* __restrict__ Bm,
    float* __restrict__ loss, const float* __restrict__ x2,
    const u16* __restrict__ X, const float* __restrict__ S0,
    int M, int N, int Kd) {
    __shared__ u16 As[128 * 64];
    __shared__ u16 Bs[128 * 64];
    const int tid = threadIdx.x;
    int btr, btc;
    swizzle_tiles(btr, btc);
    const int row0 = btr * 128, col0 = btc * 128;
    const int lane = tid & 63, wave = tid >> 6;
    const int wr = (wave >> 1) * 64, wc = (wave & 1) * 64;
    const int tx = lane & 15, quad = lane >> 4;
    const int txl = tx & 7;

    f32x4 acc[4][4] = {};

    for (int k0 = 0; k0 < Kd; k0 += 64) {
#pragma unroll
        for (int l = 0; l < 4; ++l) {
            const int lin = l * 2048 + tid * 8;
            const int r = lin >> 6;
            const int c = (((lin >> 3) & 7) ^ (r & 7)) * 8;
            gload_lds16(A + (size_t)(row0 + r) * Kd + k0 + c, &As[lin]);
        }
#pragma unroll
        for (int l = 0; l < 4; ++l) {
            const int lin = l * 2048 + tid * 8;
            const int r = lin >> 6;
            const int c = (((lin >> 3) & 7) ^ (r & 7)) * 8;
            gload_lds16(Bm + (size_t)(col0 + r) * Kd + k0 + c, &Bs[lin]);
        }
        __syncthreads();
#pragma unroll
        for (int ks = 0; ks < 2; ++ks) {
            bf16x8 af[4], bfr[4];
            const int gsw = ((ks * 4 + quad) ^ txl) * 8;
#pragma unroll
            for (int i = 0; i < 4; ++i)
                af[i] = *(const bf16x8*)&As[(wr + i * 16 + tx) * 64 + gsw];
#pragma unroll
            for (int j = 0; j < 4; ++j)
                bfr[j] = *(const bf16x8*)&Bs[(wc + j * 16 + tx) * 64 + gsw];
#pragma unroll
            for (int i = 0; i < 4; ++i)
#pragma unroll
                for (int j = 0; j < 4; ++j)
                    acc[i][j] = __builtin_amdgcn_mfma_f32_16x16x32_bf16(
                        af[i], bfr[j], acc[i][j], 0, 0, 0);
        }
        __syncthreads();
    }

    const float inv_n = 1.0f / (float)N;
#pragma unroll
    for (int i = 0; i < 4; ++i) {
#pragma unroll
        for (int r = 0; r < 4; ++r) {
            const int row = row0 + wr + i * 16 + quad * 4 + r;
            const float D = P_NULL * __expf(x2[row]) + S0[row];
            const float invD = 1.0f / D;
            float s = 0.f;
#pragma unroll
            for (int j = 0; j < 4; ++j) {
                const int col = col0 + wc + j * 16 + tx;
                const float d =
                    acc[i][j][r] * invD - bf2f(X[(size_t)row * N + col]);
                s = fmaf(d, d, s);
            }
            s += __shfl_xor(s, 1, 64);
            s += __shfl_xor(s, 2, 64);
            s += __shfl_xor(s, 4, 64);
            s += __shfl_xor(s, 8, 64);
            if (tx == 0) atomicAdd(&loss[row], s * inv_n);
        }
    }
}

// ---------------------------------------------------------------------------
// Row mean of squares of Z (B,E) bf16: x2[row] = mean(Z[row,:]^2)
// ---------------------------------------------------------------------------
__global__ __launch_bounds__(256) void rowmeansq_bf_kernel(
    const u16* __restrict__ Z, float* __restrict__ out) {
    __shared__ float sm[4];
    const float v = bf2f(Z[(size_t)blockIdx.x * E + threadIdx.x]);
    const float s = block_sum256(v * v, sm);
    if (threadIdx.x == 0) out[blockIdx.x] = s * (1.0f / (float)E);
}

// ---------------------------------------------------------------------------
extern "C" void kernel_launch(void* const* d_in, const int* in_sizes, int n_in,
                              void* d_out, int out_size, void* d_ws, size_t ws_size,
                              hipStream_t stream) {
    const float* images = (const float*)d_in[0];  // (B,G)
    const float* xa     = (const float*)d_in[1];  // (G,K)
    const float* xb     = (const float*)d_in[2];  // (E,K)
    float* out = (float*)d_out;                   // (B,)

    // workspace carve-up (u16 elements, all regions 16B-aligned)
    u16* img_bf = (u16*)d_ws;                      // B*G
    u16* xa_bf  = img_bf + (size_t)B * G;          // G*K
    u16* xaT_bf = xa_bf + (size_t)G * K;           // K*G
    u16* xb_bf  = xaT_bf + (size_t)K * G;          // E*K
    u16* xbT_bf = xb_bf + (size_t)E * K;           // K*E
    u16* e_bf   = xbT_bf + (size_t)K * E;          // B*K (unnormalized enc e)
    u16* wu_bf  = e_bf + (size_t)B * K;            // B*K (decode u)
    u16* z_bf   = wu_bf + (size_t)B * K;           // B*E
    float* c2a  = (float*)(z_bf + (size_t)B * E);  // K   --+ one memset
    float* c2b  = c2a + K;                         // K     |
    float* Svec = c2b + K;                         // 2*B --+ (S_enc, S0)
    float* x2z  = Svec + 2 * B;                    // B (fully written)
    float* Sp   = x2z + B;                         // 4*B (fully written/step)
    // Zp (4,B,E) f32 = 32MB overlays wu_bf (B*K u16 = 32MB; wu only used
    // in decode, after the step loop).
    float* Zp = (float*)wu_bf;

    (void)hipMemsetAsync(d_out, 0, (size_t)B * sizeof(float), stream);
    (void)hipMemsetAsync(c2a, 0, (size_t)(2 * K + 2 * B) * sizeof(float), stream);

    // prep: bf16 copies + transposes + column mean-squares (one read each)
    f2bf_kernel<<<(B * G) / 2048, 256, 0, stream>>>(images, img_bf, B * G);
    prep_kernel<<<dim3(K / 32, G / 32), 256, 0, stream>>>(
        xa, xa_bf, xaT_bf, c2a, G, K, 1.0f / (float)G);
    prep_kernel<<<dim3(K / 32, E / 32), 256, 0, stream>>>(
        xb, xb_bf, xbT_bf, c2b, E, K, 1.0f / (float)E);

    // encode (softmax eliminated): e = exp(images@xa*(2/G) - c2a), S_enc=rowsum
    float* S_enc = Svec;
    mfma_big_kernel<<<dim3(K / 128, B / 256), 512, 0, stream>>>(
        img_bf, xaT_bf, e_bf, c2a, S_enc, B, K, G, 2.0f / (float)G);

    // z0 = (e @ xb^T) / S_enc[row]   (== pik @ xb^T)
    mfma_z64_kernel<<<dim3(E / 64, B / 64), 256, 0, stream>>>(
        e_bf, xb_bf, z_bf, S_enc, B, E, K);

    // loop: K-split partial steps + normalize (w never hits HBM)
    for (int s = 0; s < N_STEP; ++s) {
        step_part_kernel<<<512, 512, 0, stream>>>(
            z_bf, xbT_bf, xb_bf, e_bf, c2b, Zp, Sp);
        norm_kernel<<<(B * E) / 2048, 256, 0, stream>>>(Zp, Sp, z_bf);
    }

    // decode: x2 = mean(z^2) ; u = exp(z@xb*(2/E) - c2b) ; S0 = rowsum(u)
    float* S0 = Svec + B;
    rowmeansq_bf_kernel<<<B, 256, 0, stream>>>(z_bf, x2z);
    mfma_big_kernel<<<dim3(K / 128, B / 256), 512, 0, stream>>>(
        z_bf, xbT_bf, wu_bf, c2b, S0, B, K, E, 2.0f / (float)E);

    // loss: recon = (u @ xa^T)/D[row], D = P_NULL*e^{x2}+S0 ;
    // loss[b] = mean_g (recon - images)^2  (X read as bf16 img_bf)
    mfma_loss_kernel<<<dim3(G / 128, B / 128), 256, 0, stream>>>(
        wu_bf, xa_bf, out, x2z, img_bf, S0, B, G, K);
}

// Round 13
// 402.846 us; speedup vs baseline: 1.2193x; 1.0423x over previous
//
#include <hip/hip_runtime.h>
#include <hip/hip_bf16.h>

// Problem constants (match reference)
constexpr int B = 8192;
constexpr int G = 1024;
constexpr int E = 256;
constexpr int K = 2048;
constexpr float P_NULL = 0.1f;
constexpr int N_STEP = 4;

typedef unsigned short u16;
typedef short bf16x8 __attribute__((ext_vector_type(8)));
typedef float f32x4 __attribute__((ext_vector_type(4)));

// raw-sync primitives (step kernel pipelining)
#define S_BARRIER __builtin_amdgcn_s_barrier()
#define SCHED0 __builtin_amdgcn_sched_barrier(0)
#define WAIT_VM0 asm volatile("s_waitcnt vmcnt(0)" ::: "memory")
#define WAIT_LGKM0 asm volatile("s_waitcnt lgkmcnt(0)" ::: "memory")

// ---------------------------------------------------------------------------
// bf16 <-> f32 (RNE)
// ---------------------------------------------------------------------------
__device__ inline u16 f2bf(float f) {
    union { float f; uint32_t u; } cv;
    cv.f = f;
    const uint32_t u = cv.u;
    return (u16)((u + 0x7fffu + ((u >> 16) & 1u)) >> 16);
}
__device__ inline float bf2f(u16 h) {
    union { uint32_t u; float f; } cv;
    cv.u = ((uint32_t)h) << 16;
    return cv.f;
}
__device__ inline uint4 pack8(const float* v) {
    uint4 u;
    u.x = (uint32_t)f2bf(v[0]) | ((uint32_t)f2bf(v[1]) << 16);
    u.y = (uint32_t)f2bf(v[2]) | ((uint32_t)f2bf(v[3]) << 16);
    u.z = (uint32_t)f2bf(v[4]) | ((uint32_t)f2bf(v[5]) << 16);
    u.w = (uint32_t)f2bf(v[6]) | ((uint32_t)f2bf(v[7]) << 16);
    return u;
}

// async global->LDS, 16B per lane (LDS dest is lane-linear; global src is
// per-lane and may be permuted -> XOR-swizzle is applied on the GLOBAL side)
typedef __attribute__((address_space(1))) const void* gaddr_t;
typedef __attribute__((address_space(3))) void* laddr_t;
__device__ inline void gload_lds16(const void* g, void* l) {
    __builtin_amdgcn_global_load_lds((gaddr_t)g, (laddr_t)l, 16, 0, 0);
}

// XCD-aware tile swizzle (requires gridDim.y % 8 == 0)
__device__ inline void swizzle_tiles(int& tr, int& tc) {
    const int cx = gridDim.x, cy = gridDim.y;
    const int id = blockIdx.y * cx + blockIdx.x;
    const int k = id & 7;
    const int q = id >> 3;
    tr = k * (cy >> 3) + q / cx;
    tc = q % cx;
}

// ---------------------------------------------------------------------------
// Reduction helpers (256-thread blocks, wave64)
// ---------------------------------------------------------------------------
__device__ inline float wave_sum(float v) {
#pragma unroll
    for (int off = 32; off > 0; off >>= 1) v += __shfl_down(v, off, 64);
    return v;
}

// ---------------------------------------------------------------------------
// f32 -> bf16 flat convert, 8 elems/thread
// ---------------------------------------------------------------------------
__global__ __launch_bounds__(256) void f2bf_kernel(
    const float* __restrict__ in, u16* __restrict__ out, int n) {
    const int i = (blockIdx.x * 256 + threadIdx.x) * 8;
    if (i + 7 >= n) {
        for (int j = i; j < n; ++j) out[j] = f2bf(in[j]);
        return;
    }
    const float4 a = *(const float4*)(in + i);
    const float4 b = *(const float4*)(in + i + 4);
    float v[8] = {a.x, a.y, a.z, a.w, b.x, b.y, b.z, b.w};
    *(uint4*)(out + i) = pack8(v);
}

// ---------------------------------------------------------------------------
// Fused prep: f32 (R,C) -> bf16 (R,C) copy + bf16 (C,R) transpose +
// csq[c] += (1/R) sum_r v^2.  grid (C/32, R/32), block 256.
// ---------------------------------------------------------------------------
__global__ __launch_bounds__(256) void prep_kernel(
    const float* __restrict__ in, u16* __restrict__ outN,
    u16* __restrict__ outT, float* __restrict__ csq, int R, int C,
    float inv_R) {
    __shared__ float tile[32][33];
    __shared__ float sred[8][32];
    const int bx = blockIdx.x * 32, by = blockIdx.y * 32;
    const int x = threadIdx.x & 31, y0 = threadIdx.x >> 5;
    float s = 0.f;
#pragma unroll
    for (int yy = 0; yy < 32; yy += 8) {
        const float v = in[(size_t)(by + y0 + yy) * C + bx + x];
        tile[y0 + yy][x] = v;
        outN[(size_t)(by + y0 + yy) * C + bx + x] = f2bf(v);
        s = fmaf(v, v, s);
    }
    sred[y0][x] = s;
    __syncthreads();
#pragma unroll
    for (int yy = 0; yy < 32; yy += 8)
        outT[(size_t)(bx + y0 + yy) * R + by + x] = f2bf(tile[x][y0 + yy]);
    if (y0 == 0) {
        float t = 0.f;
#pragma unroll
        for (int k2 = 0; k2 < 8; ++k2) t += sred[k2][x];
        atomicAdd(csq + bx + x, t * inv_R);
    }
}

// ---------------------------------------------------------------------------
// MFMA bf16 GEMM, 256x128 tile, 512 threads (R5-PROVEN, encode/decode):
// u = exp(alpha*acc - bias[col]) -> bf16 C; Saux[row] += row-sum.
// Measured 50.5us, VGPR 60 + 64 AGPR, zero spill.
// 8 waves (4 row-bands x 2 col-halves), 64x64 out/wave (acc[4][4]).
// ---------------------------------------------------------------------------
__global__ __launch_bounds__(512, 2) void mfma_big_kernel(
    const u16* __restrict__ A, const u16* __restrict__ Bm,
    u16* __restrict__ C, const float* __restrict__ bias,
    float* __restrict__ Saux, int M, int N, int Kd, float alpha) {
    __shared__ u16 smem[32768];  // loop: As 16384 u16 | Bs 8192 u16; epi: all
    u16* As = smem;
    u16* Bs = smem + 16384;
    const int tid = threadIdx.x;
    int btr, btc;
    swizzle_tiles(btr, btc);
    const int row0 = btr * 256, col0 = btc * 128;
    const int lane = tid & 63, wave = tid >> 6;
    const int wr = wave >> 1, wc = wave & 1;  // row-band (0..3), col-half
    const int tx = lane & 15, quad = lane >> 4;
    const int txl = tx & 7;

    f32x4 acc[4][4] = {};

    for (int k0 = 0; k0 < Kd; k0 += 64) {
#pragma unroll
        for (int l = 0; l < 4; ++l) {
            const int lin = l * 4096 + tid * 8;
            const int r = lin >> 6;
            const int c = (((lin >> 3) & 7) ^ (r & 7)) * 8;  // XOR-swizzled src
            gload_lds16(A + (size_t)(row0 + r) * Kd + k0 + c, &As[lin]);
        }
#pragma unroll
        for (int l = 0; l < 2; ++l) {
            const int lin = l * 4096 + tid * 8;
            const int r = lin >> 6;
            const int c = (((lin >> 3) & 7) ^ (r & 7)) * 8;
            gload_lds16(Bm + (size_t)(col0 + r) * Kd + k0 + c, &Bs[lin]);
        }
        __syncthreads();
#pragma unroll
        for (int ks = 0; ks < 2; ++ks) {
            bf16x8 af[4], bfr[4];
            const int gsw = ((ks * 4 + quad) ^ txl) * 8;
#pragma unroll
            for (int i = 0; i < 4; ++i)
                af[i] = *(const bf16x8*)&As[(wr * 64 + i * 16 + tx) * 64 + gsw];
#pragma unroll
            for (int j = 0; j < 4; ++j)
                bfr[j] = *(const bf16x8*)&Bs[(wc * 64 + j * 16 + tx) * 64 + gsw];
#pragma unroll
            for (int i = 0; i < 4; ++i)
#pragma unroll
                for (int j = 0; j < 4; ++j)
                    acc[i][j] = __builtin_amdgcn_mfma_f32_16x16x32_bf16(
                        af[i], bfr[j], acc[i][j], 0, 0, 0);
        }
        __syncthreads();
    }

    // ---- epilogue: per-wave 64x64 patch at wave*4096 in LDS ----
    const int wbase = wave * 4096;
#pragma unroll
    for (int i = 0; i < 4; ++i) {
        float srow[4] = {0.f, 0.f, 0.f, 0.f};
#pragma unroll
        for (int j = 0; j < 4; ++j) {
            const int pcol = j * 16 + tx;
            const float cb = bias[col0 + wc * 64 + pcol];
#pragma unroll
            for (int r = 0; r < 4; ++r) {
                const int prow = i * 16 + quad * 4 + r;  // in-wave row 0..63
                const int paddr = wbase + prow * 64 +
                    (((pcol >> 3) ^ (prow & 7)) << 3) + (pcol & 7);
                const float v = __expf(fmaf(acc[i][j][r], alpha, -cb));
                srow[r] += v;
                smem[paddr] = f2bf(v);
            }
        }
#pragma unroll
        for (int r = 0; r < 4; ++r) {
            float s = srow[r];
            s += __shfl_xor(s, 1, 64);
            s += __shfl_xor(s, 2, 64);
            s += __shfl_xor(s, 4, 64);
            s += __shfl_xor(s, 8, 64);
            if (tx == 0)
                atomicAdd(&Saux[row0 + wr * 64 + i * 16 + quad * 4 + r], s);
        }
    }
    __syncthreads();

    // ---- write-out: row rr=tid>>1 (0..255), half hs (64 cols), coalesced ----
    const int rr = tid >> 1, hs = tid & 1;
#pragma unroll
    for (int u = 0; u < 8; ++u) {
        const int c = hs * 64 + u * 8;
        const int wv = (rr >> 6) * 2 + (c >> 6);  // source wave patch
        const int rl = rr & 63, cl = c & 63;
        const int pg = ((cl >> 3) ^ (rl & 7)) << 3;
        *(uint4*)(C + (size_t)(row0 + rr) * N + col0 + c) =
            *(const uint4*)&smem[wv * 4096 + rl * 64 + pg];
    }
}

// ---------------------------------------------------------------------------
// MFMA bf16 GEMM, 64x64 tile, for z0 = (e @ xb^T) / S_enc[row].
// ---------------------------------------------------------------------------
__global__ __launch_bounds__(256) void mfma_z64_kernel(
    const u16* __restrict__ A, const u16* __restrict__ Bm,
    u16* __restrict__ C, const float* __restrict__ Srow,
    int M, int N, int Kd) {
    __shared__ u16 As[64 * 64];
    __shared__ u16 Bs[64 * 64];
    const int tid = threadIdx.x;
    int btr, btc;
    swizzle_tiles(btr, btc);
    const int row0 = btr * 64, col0 = btc * 64;
    const int lane = tid & 63, wave = tid >> 6;
    const int wr = (wave >> 1) * 32, wc = (wave & 1) * 32;
    const int tx = lane & 15, quad = lane >> 4;
    const int txl = tx & 7;

    f32x4 acc[2][2] = {};

    for (int k0 = 0; k0 < Kd; k0 += 64) {
#pragma unroll
        for (int l = 0; l < 2; ++l) {
            const int lin = l * 2048 + tid * 8;
            const int r = lin >> 6;
            const int c = (((lin >> 3) & 7) ^ (r & 7)) * 8;
            gload_lds16(A + (size_t)(row0 + r) * Kd + k0 + c, &As[lin]);
        }
#pragma unroll
        for (int l = 0; l < 2; ++l) {
            const int lin = l * 2048 + tid * 8;
            const int r = lin >> 6;
            const int c = (((lin >> 3) & 7) ^ (r & 7)) * 8;
            gload_lds16(Bm + (size_t)(col0 + r) * Kd + k0 + c, &Bs[lin]);
        }
        __syncthreads();
#pragma unroll
        for (int ks = 0; ks < 2; ++ks) {
            bf16x8 af[2], bfr[2];
            const int gsw = ((ks * 4 + quad) ^ txl) * 8;
#pragma unroll
            for (int i = 0; i < 2; ++i)
                af[i] = *(const bf16x8*)&As[(wr + i * 16 + tx) * 64 + gsw];
#pragma unroll
            for (int j = 0; j < 2; ++j)
                bfr[j] = *(const bf16x8*)&Bs[(wc + j * 16 + tx) * 64 + gsw];
#pragma unroll
            for (int i = 0; i < 2; ++i)
#pragma unroll
                for (int j = 0; j < 2; ++j)
                    acc[i][j] = __builtin_amdgcn_mfma_f32_16x16x32_bf16(
                        af[i], bfr[j], acc[i][j], 0, 0, 0);
        }
        __syncthreads();
    }

#pragma unroll
    for (int i = 0; i < 2; ++i)
#pragma unroll
        for (int r = 0; r < 4; ++r) {
            const int row = row0 + wr + i * 16 + quad * 4 + r;
            const float sc = Srow ? (1.0f / Srow[row]) : 1.0f;
#pragma unroll
            for (int j = 0; j < 2; ++j) {
                const int col = col0 + wc + j * 16 + tx;
                C[(size_t)row * N + col] = f2bf(acc[i][j][r] * sc);
            }
        }
}

// ---------------------------------------------------------------------------
// STEP (R12-proven): K-split partials, 64 rows/block x P=4 -> 512 blocks =
// 2 blocks/CU (cross-block TLP hides the full-drain staging; R12: 431->420).
// R13 change: Zp partials stored as bf16 (halves Zp write + norm read
// traffic; partial rounding error ~2^-9|z|, same order as z's own bf16
// rounding). 8 waves = 4 row-frags(16) x 2 k/e-halves. LDS 42.5KB.
// ---------------------------------------------------------------------------
constexpr int SXBT = 0;       // [32k][256e] granule-XOR8, 8192 u16
constexpr int SXB = 8192;     // [256e][32k] granule-XOR4, 8192 u16
constexpr int SES = 16384;    // [64r][36k-padded], 2304 u16
constexpr int SWS = 18688;    // [64r][36k-padded], 2304 u16
constexpr int SMEM_U16 = 20992;

__global__ __launch_bounds__(512, 4) void step_part_kernel(
    const u16* __restrict__ Z,      // (B,E) current z
    const u16* __restrict__ XbT,    // (K,E)
    const u16* __restrict__ Xb,     // (E,K)
    const u16* __restrict__ Ebf,    // (B,K) unnormalized encode weights
    const float* __restrict__ c2b,  // (K)
    u16* __restrict__ Zp,           // (4,B,E) bf16 partials
    float* __restrict__ Sp) {       // (4,B) f32 partials
    __shared__ u16 smem[SMEM_U16];
    __shared__ float redS[2][64];
    const int tid = threadIdx.x;
    const int lane = tid & 63, wave = tid >> 6;
    const int rf = wave >> 1, kf = wave & 1;  // row-frag(16), k/e-half
    const int tx = lane & 15, quad = lane >> 4;
    const int part = blockIdx.x & 3;
    const int row0 = (blockIdx.x >> 2) * 64;
    const int kbase = part * 512;
    const float ascale = 2.0f / (float)E;
    const int kcol = kf * 16 + tx;   // lane's k-col in chunk (0..31)
    const int erow_ = tid >> 3;      // e stage: row (0..63)
    const int eg_ = tid & 7;         // e stage: 4-col group
    const int ewaddr = erow_ * 36 + eg_ * 4;  // padded es/ws row stride 36

    // ---- prologue: z band [64][256] granule-XOR8 into smem[0..16384) ----
#pragma unroll
    for (int l = 0; l < 4; ++l) {
        const int lin = l * 4096 + tid * 8;
        const int r = lin >> 8, gf = (lin >> 3) & 31;
        const int eoff = ((gf & 24) | ((gf & 7) ^ (r & 7))) << 3;
        gload_lds16(Z + (size_t)(row0 + r) * E + eoff, &smem[lin]);
    }
    WAIT_VM0;
    SCHED0;
    S_BARRIER;
    SCHED0;

    // z A-frags for this wave's 16 rows: af[s], s covers E=256
    bf16x8 af[8];
    {
        const int arow = rf * 16 + tx;
#pragma unroll
        for (int s = 0; s < 8; ++s) {
            const int g = s * 4 + quad;
            const int gp = (g & 24) | ((g & 7) ^ (arow & 7));
            af[s] = *(const bf16x8*)&smem[arow * 256 + gp * 8];
        }
    }
    WAIT_LGKM0;  // af reads done before chunk staging overwrites region
    SCHED0;
    S_BARRIER;
    SCHED0;

    f32x4 acc2[8] = {};   // z' partial acc: [e-frag f] for rows rf*16..
    float srow[4] = {};   // Sw partials (this wave's rows x its kcols)

    for (int kc = 0; kc < 16; ++kc) {
        const int k0 = kbase + kc * 32;
        // ---- stage chunk (single-buffer; full drain; TLP hides) ----
#pragma unroll
        for (int l = 0; l < 2; ++l) {
            const int lin = l * 4096 + tid * 8;
            const int r = lin >> 8, gf = (lin >> 3) & 31;
            const int eoff = ((gf & 24) | ((gf & 7) ^ (r & 7))) << 3;
            gload_lds16(XbT + (size_t)(k0 + r) * E + eoff, &smem[SXBT + lin]);
        }
#pragma unroll
        for (int l = 0; l < 2; ++l) {
            const int lin = l * 4096 + tid * 8;
            const int e = lin >> 5, gq = (lin >> 3) & 3;
            const int koff = (gq ^ (e & 3) ^ ((e >> 2) & 3)) << 3;
            gload_lds16(Xb + (size_t)e * K + k0 + koff, &smem[SXB + lin]);
        }
        const uint2 ereg =
            *(const uint2*)&Ebf[(size_t)(row0 + erow_) * K + k0 + eg_ * 4];
        const float cb = c2b[k0 + kcol];
        SCHED0;
        WAIT_VM0;
        *(uint2*)&smem[SES + ewaddr] = ereg;
        WAIT_LGKM0;
        SCHED0;
        S_BARRIER;  // B0: chunk fully staged & visible
        SCHED0;

        // ---- t-part: ta = z(rows rf*16..) @ xbT(k-col = kcol) ----
        f32x4 ta = {};
#pragma unroll
        for (int s = 0; s < 8; ++s) {
            const int g = s * 4 + quad;
            const int gp = (g & 24) | ((g & 7) ^ (kcol & 7));
            const bf16x8 bfr = *(const bf16x8*)&smem[SXBT + kcol * 256 + gp * 8];
            ta = __builtin_amdgcn_mfma_f32_16x16x32_bf16(af[s], bfr, ta, 0, 0, 0);
        }

        // ---- epilogue: w = e * exp(t*ascale - cb) -> ws; Sw partial ----
#pragma unroll
        for (int r = 0; r < 4; ++r) {
            const int prow = rf * 16 + quad * 4 + r;
            const int pa = prow * 36 + kcol;
            const float ev = bf2f(smem[SES + pa]);
            const float wv = ev * __expf(fmaf(ta[r], ascale, -cb));
            srow[r] += wv;
            smem[SWS + pa] = f2bf(wv);
        }
        WAIT_LGKM0;
        SCHED0;
        S_BARRIER;  // B1: ws visible; xbts/es reads done
        SCHED0;

        // ---- z-part: acc2 += w(rows rf*16, 32k) @ xbT(32k, e=kf*128..) ----
        const bf16x8 a2 =
            *(const bf16x8*)&smem[SWS + (rf * 16 + tx) * 36 + quad * 8];
#pragma unroll
        for (int f = 0; f < 8; ++f) {
            const int ecol = kf * 128 + f * 16 + tx;
            const int gq = quad ^ (ecol & 3) ^ ((ecol >> 2) & 3);
            const bf16x8 b2 = *(const bf16x8*)&smem[SXB + ecol * 32 + gq * 8];
            acc2[f] = __builtin_amdgcn_mfma_f32_16x16x32_bf16(a2, b2, acc2[f],
                                                              0, 0, 0);
        }
        WAIT_LGKM0;
        SCHED0;
        S_BARRIER;  // B2: all LDS reads done -> next stage safe
        SCHED0;
    }

    // ---- Sw partials: reduce over tx, combine kf-halves via LDS ----
#pragma unroll
    for (int r = 0; r < 4; ++r) {
        float s = srow[r];
        s += __shfl_xor(s, 1, 64);
        s += __shfl_xor(s, 2, 64);
        s += __shfl_xor(s, 4, 64);
        s += __shfl_xor(s, 8, 64);
        if (tx == 0) redS[kf][rf * 16 + quad * 4 + r] = s;
    }
    __syncthreads();
    if (tid < 64)
        Sp[(size_t)part * B + row0 + tid] = redS[0][tid] + redS[1][tid];

    // ---- Zp stores: bf16 partials (R13) ----
#pragma unroll
    for (int f = 0; f < 8; ++f)
#pragma unroll
        for (int r = 0; r < 4; ++r) {
            const int row = rf * 16 + quad * 4 + r;
            const int e = kf * 128 + f * 16 + tx;
            Zp[((size_t)part * B + row0 + row) * E + e] = f2bf(acc2[f][r]);
        }
}

// ---------------------------------------------------------------------------
// norm: z[row][e] = (sum_p Zp[p][row][e]) / (sum_p Sp[p][row]) -> bf16.
// Zp is bf16 (R13). Optionally (final step) also emits x2[row] =
// mean(z_rounded^2), replacing the separate rowmeansq kernel.
// grid B*E/2048 = 1024, block 256, 8 elems/thread (32 threads per row).
// ---------------------------------------------------------------------------
__global__ __launch_bounds__(256) void norm_kernel(
    const u16* __restrict__ Zp, const float* __restrict__ Sp,
    u16* __restrict__ Z, float* __restrict__ x2out) {
    const int gidx = blockIdx.x * 256 + threadIdx.x;
    const int row = gidx >> 5;
    const int e0 = (gidx & 31) * 8;
    const float s = Sp[row] + Sp[B + row] + Sp[2 * B + row] + Sp[3 * B + row];
    const float inv = 1.0f / s;
    const size_t base = (size_t)row * E + e0;
    float v[8] = {0.f, 0.f, 0.f, 0.f, 0.f, 0.f, 0.f, 0.f};
#pragma unroll
    for (int p = 0; p < 4; ++p) {
        const uint4 b = *(const uint4*)(Zp + (size_t)p * B * E + base);
        const uint32_t w[4] = {b.x, b.y, b.z, b.w};
#pragma unroll
        for (int q = 0; q < 4; ++q) {
            v[q * 2] += bf2f((u16)(w[q] & 0xffffu));
            v[q * 2 + 1] += bf2f((u16)(w[q] >> 16));
        }
    }
#pragma unroll
    for (int j = 0; j < 8; ++j) v[j] *= inv;
    *(uint4*)(Z + base) = pack8(v);
    if (x2out) {
        float s2 = 0.f;
#pragma unroll
        for (int j = 0; j < 8; ++j) {
            const float zr = bf2f(f2bf(v[j]));  // match bf16-rounded z
            s2 = fmaf(zr, zr, s2);
        }
        s2 += __shfl_xor(s2, 1, 32);
        s2 += __shfl_xor(s2, 2, 32);
        s2 += __shfl_xor(s2, 4, 32);
        s2 += __shfl_xor(s2, 8, 32);
        s2 += __shfl_xor(s2, 16, 32);
        if ((gidx & 31) == 0) x2out[row] = s2 * (1.0f / (float)E);
    }
}

// ---------------------------------------------------------------------------
// MFMA bf16 GEMM (128x128 tile, 512 blocks = 2/CU) with fused MSE-loss
// epilogue: D = P_NULL*exp(x2[row]) + S0[row];
// loss[row] += (1/N)*sum_col (acc/D - X[row,col])^2   (X is bf16 img_bf)
// ---------------------------------------------------------------------------
__global__ __launch_bounds__(256) void mfma_loss_kernel(
    const u16* __restrict__ A, const u16* __restrict__ Bm,
    float* __restrict__ loss, const float* __restrict__ x2,
    const u16* __restrict__ X, const float* __restrict__ S0,
    int M, int N, int Kd) {
    __shared__ u16 As[128 * 64];
    __shared__ u16 Bs[128 * 64];
    const int tid = threadIdx.x;
    int btr, btc;
    swizzle_tiles(btr, btc);
    const int row0 = btr * 128, col0 = btc * 128;
    const int lane = tid & 63, wave = tid >> 6;
    const int wr = (wave >> 1) * 64, wc = (wave & 1) * 64;
    const int tx = lane & 15, quad = lane >> 4;
    const int txl = tx & 7;

    f32x4 acc[4][4] = {};

    for (int k0 = 0; k0 < Kd; k0 += 64) {
#pragma unroll
        for (int l = 0; l < 4; ++l) {
            const int lin = l * 2048 + tid * 8;
            const int r = lin >> 6;
            const int c = (((lin >> 3) & 7) ^ (r & 7)) * 8;
            gload_lds16(A + (size_t)(row0 + r) * Kd + k0 + c, &As[lin]);
        }
#pragma unroll
        for (int l = 0; l < 4; ++l) {
            const int lin = l * 2048 + tid * 8;
            const int r = lin >> 6;
            const int c = (((lin >> 3) & 7) ^ (r & 7)) * 8;
            gload_lds16(Bm + (size_t)(col0 + r) * Kd + k0 + c, &Bs[lin]);
        }
        __syncthreads();
#pragma unroll
        for (int ks = 0; ks < 2; ++ks) {
            bf16x8 af[4], bfr[4];
            const int gsw = ((ks * 4 + quad) ^ txl) * 8;
#pragma unroll
            for (int i = 0; i < 4; ++i)
                af[i] = *(const bf16x8*)&As[(wr + i * 16 + tx) * 64 + gsw];
#pragma unroll
            for (int j = 0; j < 4; ++j)
                bfr[j] = *(const bf16x8*)&Bs[(wc + j * 16 + tx) * 64 + gsw];
#pragma unroll
            for (int i = 0; i < 4; ++i)
#pragma unroll
                for (int j = 0; j < 4; ++j)
                    acc[i][j] = __builtin_amdgcn_mfma_f32_16x16x32_bf16(
                        af[i], bfr[j], acc[i][j], 0, 0, 0);
        }
        __syncthreads();
    }

    const float inv_n = 1.0f / (float)N;
#pragma unroll
    for (int i = 0; i < 4; ++i) {
#pragma unroll
        for (int r = 0; r < 4; ++r) {
            const int row = row0 + wr + i * 16 + quad * 4 + r;
            const float D = P_NULL * __expf(x2[row]) + S0[row];
            const float invD = 1.0f / D;
            float s = 0.f;
#pragma unroll
            for (int j = 0; j < 4; ++j) {
                const int col = col0 + wc + j * 16 + tx;
                const float d =
                    acc[i][j][r] * invD - bf2f(X[(size_t)row * N + col]);
                s = fmaf(d, d, s);
            }
            s += __shfl_xor(s, 1, 64);
            s += __shfl_xor(s, 2, 64);
            s += __shfl_xor(s, 4, 64);
            s += __shfl_xor(s, 8, 64);
            if (tx == 0) atomicAdd(&loss[row], s * inv_n);
        }
    }
}

// ---------------------------------------------------------------------------
extern "C" void kernel_launch(void* const* d_in, const int* in_sizes, int n_in,
                              void* d_out, int out_size, void* d_ws, size_t ws_size,
                              hipStream_t stream) {
    const float* images = (const float*)d_in[0];  // (B,G)
    const float* xa     = (const float*)d_in[1];  // (G,K)
    const float* xb     = (const float*)d_in[2];  // (E,K)
    float* out = (float*)d_out;                   // (B,)

    // workspace carve-up (u16 elements, all regions 16B-aligned)
    u16* img_bf = (u16*)d_ws;                      // B*G
    u16* xa_bf  = img_bf + (size_t)B * G;          // G*K
    u16* xaT_bf = xa_bf + (size_t)G * K;           // K*G
    u16* xb_bf  = xaT_bf + (size_t)K * G;          // E*K
    u16* xbT_bf = xb_bf + (size_t)E * K;           // K*E
    u16* e_bf   = xbT_bf + (size_t)K * E;          // B*K (unnormalized enc e)
    u16* wu_bf  = e_bf + (size_t)B * K;            // B*K (decode u)
    u16* z_bf   = wu_bf + (size_t)B * K;           // B*E
    float* c2a  = (float*)(z_bf + (size_t)B * E);  // K   --+ one memset
    float* c2b  = c2a + K;                         // K     |
    float* Svec = c2b + K;                         // 2*B --+ (S_enc, S0)
    float* x2z  = Svec + 2 * B;                    // B (fully written)
    float* Sp   = x2z + B;                         // 4*B (fully written/step)
    // Zp (4,B,E) bf16 = 16MB overlays wu_bf (B*K u16 = 32MB; wu only used
    // in decode, after the step loop).
    u16* Zp = wu_bf;

    (void)hipMemsetAsync(d_out, 0, (size_t)B * sizeof(float), stream);
    (void)hipMemsetAsync(c2a, 0, (size_t)(2 * K + 2 * B) * sizeof(float), stream);

    // prep: bf16 copies + transposes + column mean-squares (one read each)
    f2bf_kernel<<<(B * G) / 2048, 256, 0, stream>>>(images, img_bf, B * G);
    prep_kernel<<<dim3(K / 32, G / 32), 256, 0, stream>>>(
        xa, xa_bf, xaT_bf, c2a, G, K, 1.0f / (float)G);
    prep_kernel<<<dim3(K / 32, E / 32), 256, 0, stream>>>(
        xb, xb_bf, xbT_bf, c2b, E, K, 1.0f / (float)E);

    // encode (softmax eliminated): e = exp(images@xa*(2/G) - c2a), S_enc=rowsum
    float* S_enc = Svec;
    mfma_big_kernel<<<dim3(K / 128, B / 256), 512, 0, stream>>>(
        img_bf, xaT_bf, e_bf, c2a, S_enc, B, K, G, 2.0f / (float)G);

    // z0 = (e @ xb^T) / S_enc[row]   (== pik @ xb^T)
    mfma_z64_kernel<<<dim3(E / 64, B / 64), 256, 0, stream>>>(
        e_bf, xb_bf, z_bf, S_enc, B, E, K);

    // loop: K-split partial steps + normalize (w never hits HBM).
    // Final norm also emits x2 = mean(z^2), feeding decode directly.
    for (int s = 0; s < N_STEP; ++s) {
        step_part_kernel<<<512, 512, 0, stream>>>(
            z_bf, xbT_bf, xb_bf, e_bf, c2b, Zp, Sp);
        norm_kernel<<<(B * E) / 2048, 256, 0, stream>>>(
            Zp, Sp, z_bf, (s == N_STEP - 1) ? x2z : nullptr);
    }

    // decode: u = exp(z@xb*(2/E) - c2b) ; S0 = rowsum(u)
    float* S0 = Svec + B;
    mfma_big_kernel<<<dim3(K / 128, B / 256), 512, 0, stream>>>(
        z_bf, xbT_bf, wu_bf, c2b, S0, B, K, E, 2.0f / (float)E);

    // loss: recon = (u @ xa^T)/D[row], D = P_NULL*e^{x2}+S0 ;
    // loss[b] = mean_g (recon - images)^2  (X read as bf16 img_bf)
    mfma_loss_kernel<<<dim3(G / 128, B / 128), 256, 0, stream>>>(
        wu_bf, xa_bf, out, x2z, img_bf, S0, B, G, K);
}